// Round 15
// baseline (241.559 us; speedup 1.0000x reference)
//
#include <hip/hip_runtime.h>
#include <hip/hip_bf16.h>
#include <math.h>
#include <string.h>

typedef __attribute__((ext_vector_type(8))) short bf16x8;
typedef __attribute__((ext_vector_type(4))) float f32x4;

// Problem constants
constexpr int Bc = 2, CGc = 64, Hc = 240, Wc = 1216;
constexpr int IDXR = 4, PROP = 6;
constexpr long HW  = (long)Hc * Wc;      // 291840
constexpr long BHW = (long)Bc * HW;      // 583680

// d_out layout (floats)
constexpr long OUT0 = 0;
constexpr long OUT1 = BHW;
constexpr long OUT2 = BHW * 7;
constexpr long OUT3 = OUT2 + (long)Bc * 18 * HW;
constexpr long OUT4 = OUT3 + (long)Bc * 9 * HW;

// ---- padded NHWC bf16 guidance in ws: [b][py 0..241][px 0..1217][ic 0..63] --
constexpr int HP = Hc + 2, WPAD = Wc + 2;            // 242 x 1218
constexpr long APXB   = (long)HP * WPAD;
constexpr long A_TOT  = (long)Bc * APXB * 128;       // 75.5 MB
constexpr long WOFF   = A_TOT;
constexpr long WS_NEED = WOFF + (long)9 * 32 * 128;
// prop state table (overlaps NHWC region, dead after conv_lds):
// float4 tab4[8][BHW]; flat slots: 0-8 aff, 9-17 oy, 18-26 ox, 27 occ, 28 init
// size = 8 * BHW * 16 = 74.7 MB < A_TOT.

// prop tiling
constexpr int PR = 4, PC = 64, HLO = 6;
constexpr int TR = PR + 2 * HLO;        // 16 rows
constexpr int TC = PC + 2 * HLO + 1;    // 77 cols

__device__ __forceinline__ unsigned short f2bf(float f) {
  __hip_bfloat16 h = __float2bfloat16(f);
  return __builtin_bit_cast(unsigned short, h);
}

// horizontal pair load with zero padding; interior = one 8B load
__device__ __forceinline__ void row2(const float* __restrict__ img, int yy, int x0,
                                     float& a, float& b) {
  if (yy >= 0 && yy < Hc) {
    if (x0 >= 0 && x0 < Wc - 1) {
      float2 v;
      __builtin_memcpy(&v, img + (long)yy * Wc + x0, 8);
      a = v.x; b = v.y;
    } else {
      a = (x0 >= 0 && x0 < Wc)         ? img[(long)yy * Wc + x0]     : 0.f;
      b = (x0 + 1 >= 0 && x0 + 1 < Wc) ? img[(long)yy * Wc + x0 + 1] : 0.f;
    }
  } else { a = 0.f; b = 0.f; }
}

__device__ __forceinline__ float bilin(const float* __restrict__ img, float y, float x) {
  float y0f = floorf(y), x0f = floorf(x);
  int y0 = (int)y0f, x0 = (int)x0f;
  float wy = y - y0f, wx = x - x0f;
  float v00, v01, v10, v11;
  row2(img, y0,     x0, v00, v01);
  row2(img, y0 + 1, x0, v10, v11);
  float top = v00 + wx * (v01 - v00);
  float bot = v10 + wx * (v11 - v10);
  return top + wy * (bot - top);
}

// bilinear out of a staged tile (zeros outside image already staged) with
// global fallback when the sample footprint leaves the tile.
__device__ __forceinline__ float bilin_tile(
    const float (*tile)[TC], const float* __restrict__ db,
    int y0, int x0, float sy, float sx) {
  float yf = floorf(sy), xf = floorf(sx);
  int iy = (int)yf, ix = (int)xf;
  float wy = sy - yf, wx = sx - xf;
  if (iy >= y0 - HLO && iy + 1 <= y0 + PR - 1 + HLO &&
      ix >= x0 - HLO && ix + 1 <= x0 + PC - 1 + HLO) {
    int ly = iy - (y0 - HLO), lx = ix - (x0 - HLO);
    float v00 = tile[ly][lx],     v01 = tile[ly][lx + 1];
    float v10 = tile[ly + 1][lx], v11 = tile[ly + 1][lx + 1];
    float top = v00 + wx * (v01 - v00);
    float bot = v10 + wx * (v11 - v10);
    return top + wy * (bot - top);
  }
  return bilin(db, sy, sx);
}

__device__ __forceinline__ void stage_tile(
    float (*tile)[TC], const float* __restrict__ db, int y0, int x0, int tid) {
  for (int i = tid; i < TR * TC; i += 256) {
    int rr = i / TC, cc = i - rr * TC;
    int gy = y0 - HLO + rr, gx = x0 - HLO + cc;
    tile[rr][cc] = (gy >= 0 && gy < Hc && gx >= 0 && gx < Wc)
                       ? db[(long)gy * Wc + gx] : 0.f;
  }
}

// ---------------- NCHW f32 -> padded NHWC bf16 (tiled transpose) -------------
__global__ __launch_bounds__(256) void nhwc_kernel(
    const float* __restrict__ g, char* __restrict__ ws) {
  __shared__ __align__(16) char tileb[64 * 132];
  const int tid = threadIdx.x;
  const int x0 = blockIdx.x * 64;
  const int y  = blockIdx.y;
  const int bz = blockIdx.z;
  const float* gb = g + (long)bz * CGc * HW + (long)y * Wc + x0;
  const int px = tid & 63, wv = tid >> 6;
#pragma unroll
  for (int k = 0; k < 16; ++k) {
    int ic = k * 4 + wv;
    float v = gb[(long)ic * HW + px];
    *reinterpret_cast<unsigned short*>(tileb + px * 132 + ic * 2) = f2bf(v);
  }
  __syncthreads();
  const int opx = tid >> 2, q = tid & 3;
  unsigned int u[8];
#pragma unroll
  for (int j = 0; j < 8; ++j)
    u[j] = *reinterpret_cast<unsigned int*>(tileb + opx * 132 + q * 32 + j * 4);
  char* dst = ws + ((long)(bz * HP + y + 1) * WPAD + x0 + 1 + opx) * 128 + q * 32;
  reinterpret_cast<uint4*>(dst)[0] = make_uint4(u[0], u[1], u[2], u[3]);
  reinterpret_cast<uint4*>(dst)[1] = make_uint4(u[4], u[5], u[6], u[7]);
}

// ---------------- zero the pad border ---------------------------------------
__global__ __launch_bounds__(256) void border_kernel(char* __restrict__ ws) {
  constexpr int NB = 2 * WPAD + 2 * (HP - 2);
  long i = (long)blockIdx.x * 256 + threadIdx.x;
  if (i >= (long)Bc * NB) return;
  int bz = (int)(i / NB);
  int r  = (int)(i - (long)bz * NB);
  int py, px;
  if (r < WPAD)            { py = 0;      px = r; }
  else if (r < 2 * WPAD)   { py = HP - 1; px = r - WPAD; }
  else { int qq = r - 2 * WPAD; py = 1 + (qq >> 1); px = (qq & 1) ? (WPAD - 1) : 0; }
  char* p = ws + ((long)(bz * HP + py) * WPAD + px) * 128;
  uint4 z = make_uint4(0, 0, 0, 0);
#pragma unroll
  for (int j = 0; j < 8; ++j) reinterpret_cast<uint4*>(p)[j] = z;
}

// ---------------- W: OIHW f32 -> [tap9][oc32][ic64] bf16 (72 blocks) ---------
__global__ __launch_bounds__(256) void wconv_kernel(
    const float* __restrict__ w, char* __restrict__ ws) {
  char* wd = ws + WOFF;
  int idx = blockIdx.x * 256 + threadIdx.x;
  if (idx < 24 * 64 * 9) {
    int oc = idx / 576, r = idx - oc * 576;
    int ic = r / 9, tap = r - ic * 9;
    *reinterpret_cast<unsigned short*>(wd + tap * 4096 + oc * 128 + ic * 2) = f2bf(w[idx]);
  } else if (idx < 32 * 64 * 9) {
    int i2 = idx - 24 * 64 * 9;
    int oc = 24 + i2 / 576, r = i2 % 576;
    int ic = r / 9, tap = r % 9;
    *reinterpret_cast<unsigned short*>(wd + tap * 4096 + oc * 128 + ic * 2) = 0;
  }
}

// ---------------- LDS-staged MFMA conv (round-10 proven) ---------------------
constexpr int CTILE_BYTES = 6 * 66 * 128;   // 50688
constexpr int CUNITS = CTILE_BYTES / 16;    // 3168

__global__ __launch_bounds__(256) void conv_lds_kernel(
    const char* __restrict__ ws, const float* __restrict__ bias,
    float* __restrict__ out) {
  __shared__ __align__(16) char smemA[CTILE_BYTES];
  const int tid  = threadIdx.x;
  const int lane = tid & 63, wv = tid >> 6;
  const int lrow = lane & 15, lgrp = lane >> 4;
  const int x0 = blockIdx.x * 64;
  const int y0 = blockIdx.y * 4;
  const int bz = blockIdx.z;

  const char* Abase = ws + ((long)(bz * HP + y0) * WPAD + x0) * 128;
#pragma unroll
  for (int it = 0; it < 13; ++it) {
    int u = it * 256 + tid;
    if (u < CUNITS) {
      int pxl = u >> 3, j = u & 7;
      int r = pxl / 66, col = pxl - r * 66;
      uint4 v = *reinterpret_cast<const uint4*>(
          Abase + ((long)r * WPAD + col) * 128 + j * 16);
      int ldsb = pxl * 128 + ((j ^ (col & 7)) << 4);
      *reinterpret_cast<uint4*>(smemA + ldsb) = v;
    }
  }
  __syncthreads();

  const char* Wb = ws + WOFF + (long)lrow * 128 + lgrp * 16;

  f32x4 acc[4][2];
#pragma unroll
  for (int h = 0; h < 4; ++h)
#pragma unroll
    for (int nt = 0; nt < 2; ++nt) acc[h][nt] = (f32x4){0.f, 0.f, 0.f, 0.f};

#pragma unroll
  for (int tap = 0; tap < 9; ++tap) {
    const int dy = tap / 3, dx = tap - dy * 3;
    const char* Wt = Wb + tap * 4096;
#pragma unroll
    for (int ks = 0; ks < 2; ++ks) {
      bf16x8 wf0 = *reinterpret_cast<const bf16x8*>(Wt + ks * 64);
      bf16x8 wf1 = *reinterpret_cast<const bf16x8*>(Wt + 2048 + ks * 64);
#pragma unroll
      for (int h = 0; h < 4; ++h) {
        const int colc = lrow + dx + h * 16;
        int abyte = ((wv + dy) * 66 + colc) * 128 +
                    ((((ks << 2) + lgrp) ^ (colc & 7)) << 4);
        bf16x8 af = *reinterpret_cast<const bf16x8*>(smemA + abyte);
        acc[h][0] = __builtin_amdgcn_mfma_f32_16x16x32_bf16(af, wf0, acc[h][0], 0, 0, 0);
        acc[h][1] = __builtin_amdgcn_mfma_f32_16x16x32_bf16(af, wf1, acc[h][1], 0, 0, 0);
      }
    }
  }

  const int y = y0 + wv;
#pragma unroll
  for (int h = 0; h < 4; ++h) {
    const int xx = x0 + h * 16 + lgrp * 4;
#pragma unroll
    for (int nt = 0; nt < 2; ++nt) {
      int oc = nt * 16 + lrow;
      if (oc >= 24) continue;
      float bv = bias[oc];
      long dst;
      if (oc < 16) {
        int n = oc >> 1, cd = oc & 1;
        int mm = (n < IDXR) ? n : n + 1;
        dst = OUT2 + (long)(bz * 18 + 2 * mm + cd) * HW;
      } else {
        int i2 = oc - 16;
        int mm = (i2 < IDXR) ? i2 : i2 + 1;
        dst = OUT3 + (long)(bz * 9 + mm) * HW;
      }
      f32x4 v = acc[h][nt];
      float4 st = make_float4(v[0] + bv, v[1] + bv, v[2] + bv, v[3] + bv);
      *reinterpret_cast<float4*>(&out[dst + (long)y * Wc + xx]) = st;
    }
  }
}

// ---------------- fused prep + prop step 0 (tiled; writes state table) -------
__global__ __launch_bounds__(256) void prep_prop0_kernel(
    const float* __restrict__ conf, const float* __restrict__ scale_p,
    const float* __restrict__ occm, const float* __restrict__ initd,
    float* __restrict__ out, float4* __restrict__ tab4) {
  __shared__ float tile[TR][TC];
  __shared__ float ctile[TR][TC];
  const int tid = threadIdx.x;
  const int x0 = blockIdx.x * PC;
  const int y0 = blockIdx.y * PR;
  const int b  = blockIdx.z;
  const float* db    = initd + (long)b * HW;
  const float* confb = conf  + (long)b * HW;
  stage_tile(tile,  db,    y0, x0, tid);
  stage_tile(ctile, confb, y0, x0, tid);
  __syncthreads();

  const int y = y0 + (tid >> 6);
  const int x = x0 + (tid & 63);
  long rem = (long)y * Wc + x;
  long p = (long)b * HW + rem;

  const float inv_scale = 1.f / (scale_p[0] + 1e-8f);
  float* off  = out + OUT2 + (long)b * 18 * HW + rem;
  float* affp = out + OUT3 + (long)b * 9  * HW + rem;

  float affr[9], oyr[9], oxr[9];
  float asum = 0.f;
#pragma unroll
  for (int m = 0; m < 8; m++) {
    int n = (m < IDXR) ? m : m + 1;
    float oy  = off[(long)(2 * n) * HW];
    float ox  = off[(long)(2 * n + 1) * HW];
    float raw = affp[(long)n * HW];
    float avv = tanhf(raw) * inv_scale;
    float cs  = bilin_tile(ctile, confb, y0, x0, (float)y + oy, (float)x + ox);
    affr[n] = avv * cs;
    oyr[n] = oy; oxr[n] = ox;
    asum += fabsf(affr[n]);
  }
  float s = fmaxf(asum + 1e-5f, 1.0f);
  float inv_s = 1.f / s;
  float total = 0.f;
#pragma unroll
  for (int m = 0; m < 8; m++) {
    int n = (m < IDXR) ? m : m + 1;
    affr[n] *= inv_s; total += affr[n];
  }
  affr[IDXR] = 1.f - total;
  oyr[IDXR] = 0.f; oxr[IDXR] = 0.f;
#pragma unroll
  for (int n = 0; n < 9; n++) affp[(long)n * HW] = affr[n];
  off[(long)(2 * IDXR) * HW]     = 0.f;
  off[(long)(2 * IDXR + 1) * HW] = 0.f;
  if (p == 0) out[OUT4] = scale_p[0];

  // ---- propagation step 0 (from initial_disp via LDS tile) ----
  float occv  = occm[p];
  float initv = db[rem];
  float acc = 0.f;
#pragma unroll
  for (int k = 0; k < 9; k++) {
    float sy = (float)(y + k / 3 - 1) + oyr[k];
    float sx = (float)(x + k % 3 - 1) + oxr[k];
    acc = fmaf(affr[k], bilin_tile(tile, db, y0, x0, sy, sx), acc);
  }
  acc = fmaxf(acc, 0.f);
  float res = (1.f - occv) * acc + occv * initv;
  out[OUT1 + p] = res;

  // ---- write packed state table (SoA of float4: coalesced) ----
  float fl[32];
#pragma unroll
  for (int k = 0; k < 9; k++) { fl[k] = affr[k]; fl[9 + k] = oyr[k]; fl[18 + k] = oxr[k]; }
  fl[27] = occv; fl[28] = initv; fl[29] = 0.f; fl[30] = 0.f; fl[31] = 0.f;
#pragma unroll
  for (int g = 0; g < 8; g++)
    tab4[(long)g * BHW + p] = make_float4(fl[4 * g], fl[4 * g + 1], fl[4 * g + 2], fl[4 * g + 3]);
}

// ---------------- propagation steps 1..5 (tiled disp + packed table) ---------
__global__ __launch_bounds__(256) void prop_tab_kernel(
    const float* __restrict__ dispPrev, const float4* __restrict__ tab4,
    float* __restrict__ out, int t) {
  __shared__ float tile[TR][TC];
  const int tid = threadIdx.x;
  const int x0 = blockIdx.x * PC;
  const int y0 = blockIdx.y * PR;
  const int b  = blockIdx.z;
  const float* db = dispPrev + (long)b * HW;
  stage_tile(tile, db, y0, x0, tid);
  __syncthreads();

  const int y = y0 + (tid >> 6);
  const int x = x0 + (tid & 63);
  long rem = (long)y * Wc + x;
  long p = (long)b * HW + rem;

  float fl[32];
#pragma unroll
  for (int g = 0; g < 8; g++) {
    float4 v = tab4[(long)g * BHW + p];
    fl[4 * g] = v.x; fl[4 * g + 1] = v.y; fl[4 * g + 2] = v.z; fl[4 * g + 3] = v.w;
  }

  float acc = 0.f;
#pragma unroll
  for (int k = 0; k < 9; k++) {
    float sy = (float)(y + k / 3 - 1) + fl[9 + k];
    float sx = (float)(x + k % 3 - 1) + fl[18 + k];
    acc = fmaf(fl[k], bilin_tile(tile, db, y0, x0, sy, sx), acc);
  }
  acc = fmaxf(acc, 0.f);
  float res = (1.f - fl[27]) * acc + fl[27] * fl[28];
  out[OUT1 + (long)t * BHW + p] = res;
  if (t == PROP - 1) out[OUT0 + p] = res;
}

// ================= legacy fallback path (ws too small) =======================
constexpr int TY = 8, TX = 32;
constexpr int AR = TY + 2, AC = TX + 2;
constexpr int A_BYTES = AR * AC * CGc * 2;
constexpr int W_BYTES = 9 * 32 * 32 * 2;

__global__ __launch_bounds__(256) void conv_mfma_kernel(
    const float* __restrict__ g, const float* __restrict__ wsrc,
    const float* __restrict__ bias, float* __restrict__ out) {
  __shared__ __align__(16) char smemA[A_BYTES];
  __shared__ __align__(16) char smemW[W_BYTES];
  const int tid = threadIdx.x;
  const int x0 = blockIdx.x * TX;
  const int y0 = blockIdx.y * TY;
  const int bz = blockIdx.z;
  const float* gb = g + (long)bz * CGc * HW;
  for (int w = tid; w < AR * AC * 32; w += 256) {
    int c  = w % AC;
    int t2 = w / AC;
    int icp = t2 & 31;
    int r   = t2 >> 5;
    int y = y0 + r - 1, x = x0 + c - 1;
    float v0 = 0.f, v1 = 0.f;
    if (y >= 0 && y < Hc && x >= 0 && x < Wc) {
      const float* p = gb + (long)(2 * icp) * HW + (long)y * Wc + x;
      v0 = p[0]; v1 = p[HW];
    }
    unsigned int pk = (unsigned int)f2bf(v0) | ((unsigned int)f2bf(v1) << 16);
    int byte = (r * AC + c) * 128 + icp * 4;
    byte ^= (c & 7) << 4;
    *reinterpret_cast<unsigned int*>(smemA + byte) = pk;
  }
  auto stageW = [&](int hs) {
    for (int idx = tid; idx < 24 * 32 * 9; idx += 256) {
      int oc  = idx / 288;
      int r1  = idx - oc * 288;
      int icl = r1 / 9;
      int tap = r1 - icl * 9;
      float f = wsrc[idx + 288 * (oc + hs)];
      int byte = (tap * 32 + oc) * 64 + icl * 2;
      byte ^= (oc & 7) << 4;
      *reinterpret_cast<unsigned short*>(smemW + byte) = f2bf(f);
    }
  };
  stageW(0);
  __syncthreads();
  const int wid  = tid >> 6;
  const int lane = tid & 63;
  const int lrow = lane & 15;
  const int lgrp = lane >> 4;
  f32x4 acc[4][2];
#pragma unroll
  for (int m = 0; m < 4; m++)
#pragma unroll
    for (int nt = 0; nt < 2; nt++) acc[m][nt] = (f32x4){0.f, 0.f, 0.f, 0.f};
  for (int ks = 0; ks < 2; ++ks) {
    if (ks) { __syncthreads(); stageW(1); __syncthreads(); }
#pragma unroll
    for (int tap = 0; tap < 9; ++tap) {
      const int dy = tap / 3, dx = tap - dy * 3;
      int bb = (tap * 32 + lrow) * 64 + lgrp * 16;
      int bbyte0 = bb ^ ((lrow & 7) << 4);
      int bbyte1 = (bb + 16 * 64) ^ ((lrow & 7) << 4);
      bf16x8 bf0 = *reinterpret_cast<const bf16x8*>(smemW + bbyte0);
      bf16x8 bf1 = *reinterpret_cast<const bf16x8*>(smemW + bbyte1);
#pragma unroll
      for (int dr = 0; dr < 2; ++dr) {
        const int rin = 2 * wid + dr + dy;
#pragma unroll
        for (int h = 0; h < 2; ++h) {
          const int cin = h * 16 + lrow + dx;
          int abyte = ((rin * AC + cin) * 128 + ks * 64 + lgrp * 16) ^ ((cin & 7) << 4);
          bf16x8 af = *reinterpret_cast<const bf16x8*>(smemA + abyte);
          acc[dr * 2 + h][0] = __builtin_amdgcn_mfma_f32_16x16x32_bf16(af, bf0, acc[dr * 2 + h][0], 0, 0, 0);
          acc[dr * 2 + h][1] = __builtin_amdgcn_mfma_f32_16x16x32_bf16(af, bf1, acc[dr * 2 + h][1], 0, 0, 0);
        }
      }
    }
  }
#pragma unroll
  for (int dr = 0; dr < 2; ++dr) {
    const int yy = y0 + 2 * wid + dr;
#pragma unroll
    for (int h = 0; h < 2; ++h) {
      const int xx = x0 + h * 16 + lgrp * 4;
#pragma unroll
      for (int nt = 0; nt < 2; ++nt) {
        int oc = nt * 16 + lrow;
        if (oc >= 24) continue;
        float bv = bias[oc];
        long dst;
        if (oc < 16) {
          int n = oc >> 1, cd = oc & 1;
          int mm = (n < IDXR) ? n : n + 1;
          dst = OUT2 + (long)(bz * 18 + 2 * mm + cd) * HW;
        } else {
          int i2 = oc - 16;
          int mm = (i2 < IDXR) ? i2 : i2 + 1;
          dst = OUT3 + (long)(bz * 9 + mm) * HW;
        }
        f32x4 v = acc[dr * 2 + h][nt];
        float4 st = make_float4(v[0] + bv, v[1] + bv, v[2] + bv, v[3] + bv);
        *reinterpret_cast<float4*>(&out[dst + (long)yy * Wc + xx]) = st;
      }
    }
  }
}

__global__ __launch_bounds__(256) void prep_kernel(
    const float* __restrict__ conf, const float* __restrict__ scale_p,
    float* __restrict__ out) {
  long p = (long)blockIdx.x * 256 + threadIdx.x;
  if (p >= BHW) return;
  int b = (int)(p / HW);
  long rem = p - (long)b * HW;
  int y = (int)(rem / Wc);
  int x = (int)(rem - (long)y * Wc);
  const float inv_scale = 1.f / (scale_p[0] + 1e-8f);
  const float* confb = conf + (long)b * HW;
  float* off  = out + OUT2 + (long)b * 18 * HW + rem;
  float* affp = out + OUT3 + (long)b * 9  * HW + rem;
  float a[8];
  float asum = 0.f;
#pragma unroll
  for (int m = 0; m < 8; m++) {
    int n = (m < IDXR) ? m : m + 1;
    float oy  = off[(long)(2 * n) * HW];
    float ox  = off[(long)(2 * n + 1) * HW];
    float raw = affp[(long)n * HW];
    float av  = tanhf(raw) * inv_scale;
    float cs  = bilin(confb, (float)y + oy, (float)x + ox);
    a[m] = av * cs;
    asum += fabsf(a[m]);
  }
  float s = fmaxf(asum + 1e-5f, 1.0f);
  float inv_s = 1.f / s;
  float total = 0.f;
#pragma unroll
  for (int m = 0; m < 8; m++) { a[m] *= inv_s; total += a[m]; }
  float aref = 1.f - total;
#pragma unroll
  for (int m = 0; m < 8; m++) {
    int n = (m < IDXR) ? m : m + 1;
    affp[(long)n * HW] = a[m];
  }
  affp[(long)IDXR * HW] = aref;
  off[(long)(2 * IDXR) * HW]     = 0.f;
  off[(long)(2 * IDXR + 1) * HW] = 0.f;
  if (p == 0) out[OUT4] = scale_p[0];
}

__global__ __launch_bounds__(256) void prop_kernel(
    const float* __restrict__ dispPrev,
    const float* __restrict__ occ, const float* __restrict__ initd,
    float* __restrict__ out, int t) {
  long p = (long)blockIdx.x * 256 + threadIdx.x;
  if (p >= BHW) return;
  int b = (int)(p / HW);
  long rem = p - (long)b * HW;
  int y = (int)(rem / Wc);
  int x = (int)(rem - (long)y * Wc);
  const float* off  = out + OUT2 + (long)b * 18 * HW + rem;
  const float* affp = out + OUT3 + (long)b * 9  * HW + rem;
  const float* db   = dispPrev + (long)b * HW;
  float acc = 0.f;
#pragma unroll
  for (int k = 0; k < 9; k++) {
    float oy = off[(long)(2 * k) * HW];
    float ox = off[(long)(2 * k + 1) * HW];
    float av = affp[(long)k * HW];
    float sy = (float)(y + k / 3 - 1) + oy;
    float sx = (float)(x + k % 3 - 1) + ox;
    acc = fmaf(av, bilin(db, sy, sx), acc);
  }
  acc = fmaxf(acc, 0.f);
  float o = occ[p];
  float res = (1.f - o) * acc + o * initd[p];
  out[OUT1 + (long)t * BHW + p] = res;
  if (t == PROP - 1) out[OUT0 + p] = res;
}

extern "C" void kernel_launch(void* const* d_in, const int* in_sizes, int n_in,
                              void* d_out, int out_size, void* d_ws, size_t ws_size,
                              hipStream_t stream) {
  const float* initd = (const float*)d_in[0];
  const float* occ   = (const float*)d_in[1];
  const float* conf  = (const float*)d_in[2];
  const float* guid  = (const float*)d_in[3];
  const float* cw    = (const float*)d_in[4];
  const float* cb    = (const float*)d_in[5];
  const float* csc   = (const float*)d_in[6];
  float* out = (float*)d_out;
  int nblk = (int)((BHW + 255) / 256);  // 2280

  if (ws_size >= (size_t)WS_NEED) {
    char* ws = (char*)d_ws;
    nhwc_kernel<<<dim3(Wc / 64, Hc, Bc), 256, 0, stream>>>(guid, ws);
    border_kernel<<<(Bc * (2 * WPAD + 2 * (HP - 2)) + 255) / 256, 256, 0, stream>>>(ws);
    wconv_kernel<<<72, 256, 0, stream>>>(cw, ws);
    conv_lds_kernel<<<dim3(Wc / 64, Hc / 4, Bc), 256, 0, stream>>>(ws, cb, out);

    float4* tab4 = (float4*)ws;  // overlaps NHWC region (dead after conv_lds)
    dim3 pgrid(Wc / PC, Hc / PR, Bc);  // (19, 60, 2)
    prep_prop0_kernel<<<pgrid, 256, 0, stream>>>(conf, csc, occ, initd, out, tab4);
    for (int t = 1; t < PROP; t++) {
      const float* dp = out + OUT1 + (long)(t - 1) * BHW;
      prop_tab_kernel<<<pgrid, 256, 0, stream>>>(dp, tab4, out, t);
    }
  } else {
    conv_mfma_kernel<<<dim3(Wc / TX, Hc / TY, Bc), 256, 0, stream>>>(guid, cw, cb, out);
    prep_kernel<<<nblk, 256, 0, stream>>>(conf, csc, out);
    for (int t = 0; t < PROP; t++) {
      const float* dp = (t == 0) ? initd : (out + OUT1 + (long)(t - 1) * BHW);
      prop_kernel<<<nblk, 256, 0, stream>>>(dp, occ, initd, out, t);
    }
  }
}

// Round 16
// 223.275 us; speedup vs baseline: 1.0819x; 1.0819x over previous
//
#include <hip/hip_runtime.h>
#include <hip/hip_bf16.h>
#include <math.h>
#include <string.h>

typedef __attribute__((ext_vector_type(8))) short bf16x8;
typedef __attribute__((ext_vector_type(4))) float f32x4;

// Problem constants
constexpr int Bc = 2, CGc = 64, Hc = 240, Wc = 1216;
constexpr int IDXR = 4, PROP = 6;
constexpr long HW  = (long)Hc * Wc;      // 291840
constexpr long BHW = (long)Bc * HW;      // 583680

// d_out layout (floats)
constexpr long OUT0 = 0;
constexpr long OUT1 = BHW;
constexpr long OUT2 = BHW * 7;
constexpr long OUT3 = OUT2 + (long)Bc * 18 * HW;
constexpr long OUT4 = OUT3 + (long)Bc * 9 * HW;

// ---- padded NHWC bf16 guidance in ws: [b][py 0..241][px 0..1217][ic 0..63] --
constexpr int HP = Hc + 2, WPAD = Wc + 2;            // 242 x 1218
constexpr long APXB   = (long)HP * WPAD;
constexpr long A_TOT  = (long)Bc * APXB * 128;       // 75.5 MB
constexpr long WOFF   = A_TOT;
constexpr long WS_NEED = WOFF + (long)9 * 32 * 128;

// prop tiling
constexpr int PR = 4, PC = 64, HLO = 6;
constexpr int TR = PR + 2 * HLO;        // 16 rows
constexpr int TC = PC + 2 * HLO + 1;    // 77 cols

__device__ __forceinline__ unsigned short f2bf(float f) {
  __hip_bfloat16 h = __float2bfloat16(f);
  return __builtin_bit_cast(unsigned short, h);
}

// horizontal pair load with zero padding; interior = one 8B load
__device__ __forceinline__ void row2(const float* __restrict__ img, int yy, int x0,
                                     float& a, float& b) {
  if (yy >= 0 && yy < Hc) {
    if (x0 >= 0 && x0 < Wc - 1) {
      float2 v;
      __builtin_memcpy(&v, img + (long)yy * Wc + x0, 8);
      a = v.x; b = v.y;
    } else {
      a = (x0 >= 0 && x0 < Wc)         ? img[(long)yy * Wc + x0]     : 0.f;
      b = (x0 + 1 >= 0 && x0 + 1 < Wc) ? img[(long)yy * Wc + x0 + 1] : 0.f;
    }
  } else { a = 0.f; b = 0.f; }
}

__device__ __forceinline__ float bilin(const float* __restrict__ img, float y, float x) {
  float y0f = floorf(y), x0f = floorf(x);
  int y0 = (int)y0f, x0 = (int)x0f;
  float wy = y - y0f, wx = x - x0f;
  float v00, v01, v10, v11;
  row2(img, y0,     x0, v00, v01);
  row2(img, y0 + 1, x0, v10, v11);
  float top = v00 + wx * (v01 - v00);
  float bot = v10 + wx * (v11 - v10);
  return top + wy * (bot - top);
}

// bilinear out of a staged tile (zeros outside image already staged) with
// global fallback when the sample footprint leaves the tile.
__device__ __forceinline__ float bilin_tile(
    const float (*tile)[TC], const float* __restrict__ db,
    int y0, int x0, float sy, float sx) {
  float yf = floorf(sy), xf = floorf(sx);
  int iy = (int)yf, ix = (int)xf;
  float wy = sy - yf, wx = sx - xf;
  if (iy >= y0 - HLO && iy + 1 <= y0 + PR - 1 + HLO &&
      ix >= x0 - HLO && ix + 1 <= x0 + PC - 1 + HLO) {
    int ly = iy - (y0 - HLO), lx = ix - (x0 - HLO);
    float v00 = tile[ly][lx],     v01 = tile[ly][lx + 1];
    float v10 = tile[ly + 1][lx], v11 = tile[ly + 1][lx + 1];
    float top = v00 + wx * (v01 - v00);
    float bot = v10 + wx * (v11 - v10);
    return top + wy * (bot - top);
  }
  return bilin(db, sy, sx);
}

__device__ __forceinline__ void stage_tile(
    float (*tile)[TC], const float* __restrict__ db, int y0, int x0, int tid) {
  for (int i = tid; i < TR * TC; i += 256) {
    int rr = i / TC, cc = i - rr * TC;
    int gy = y0 - HLO + rr, gx = x0 - HLO + cc;
    tile[rr][cc] = (gy >= 0 && gy < Hc && gx >= 0 && gx < Wc)
                       ? db[(long)gy * Wc + gx] : 0.f;
  }
}

// ---------------- NCHW f32 -> padded NHWC bf16 (tiled transpose) -------------
__global__ __launch_bounds__(256) void nhwc_kernel(
    const float* __restrict__ g, char* __restrict__ ws) {
  __shared__ __align__(16) char tileb[64 * 132];
  const int tid = threadIdx.x;
  const int x0 = blockIdx.x * 64;
  const int y  = blockIdx.y;
  const int bz = blockIdx.z;
  const float* gb = g + (long)bz * CGc * HW + (long)y * Wc + x0;
  const int px = tid & 63, wv = tid >> 6;
#pragma unroll
  for (int k = 0; k < 16; ++k) {
    int ic = k * 4 + wv;
    float v = gb[(long)ic * HW + px];
    *reinterpret_cast<unsigned short*>(tileb + px * 132 + ic * 2) = f2bf(v);
  }
  __syncthreads();
  const int opx = tid >> 2, q = tid & 3;
  unsigned int u[8];
#pragma unroll
  for (int j = 0; j < 8; ++j)
    u[j] = *reinterpret_cast<unsigned int*>(tileb + opx * 132 + q * 32 + j * 4);
  char* dst = ws + ((long)(bz * HP + y + 1) * WPAD + x0 + 1 + opx) * 128 + q * 32;
  reinterpret_cast<uint4*>(dst)[0] = make_uint4(u[0], u[1], u[2], u[3]);
  reinterpret_cast<uint4*>(dst)[1] = make_uint4(u[4], u[5], u[6], u[7]);
}

// ---------------- zero the pad border ---------------------------------------
__global__ __launch_bounds__(256) void border_kernel(char* __restrict__ ws) {
  constexpr int NB = 2 * WPAD + 2 * (HP - 2);
  long i = (long)blockIdx.x * 256 + threadIdx.x;
  if (i >= (long)Bc * NB) return;
  int bz = (int)(i / NB);
  int r  = (int)(i - (long)bz * NB);
  int py, px;
  if (r < WPAD)            { py = 0;      px = r; }
  else if (r < 2 * WPAD)   { py = HP - 1; px = r - WPAD; }
  else { int qq = r - 2 * WPAD; py = 1 + (qq >> 1); px = (qq & 1) ? (WPAD - 1) : 0; }
  char* p = ws + ((long)(bz * HP + py) * WPAD + px) * 128;
  uint4 z = make_uint4(0, 0, 0, 0);
#pragma unroll
  for (int j = 0; j < 8; ++j) reinterpret_cast<uint4*>(p)[j] = z;
}

// ---------------- W: OIHW f32 -> [tap9][oc32][ic64] bf16 (72 blocks) ---------
__global__ __launch_bounds__(256) void wconv_kernel(
    const float* __restrict__ w, char* __restrict__ ws) {
  char* wd = ws + WOFF;
  int idx = blockIdx.x * 256 + threadIdx.x;
  if (idx < 24 * 64 * 9) {
    int oc = idx / 576, r = idx - oc * 576;
    int ic = r / 9, tap = r - ic * 9;
    *reinterpret_cast<unsigned short*>(wd + tap * 4096 + oc * 128 + ic * 2) = f2bf(w[idx]);
  } else if (idx < 32 * 64 * 9) {
    int i2 = idx - 24 * 64 * 9;
    int oc = 24 + i2 / 576, r = i2 % 576;
    int ic = r / 9, tap = r % 9;
    *reinterpret_cast<unsigned short*>(wd + tap * 4096 + oc * 128 + ic * 2) = 0;
  }
}

// ---------------- fused conv + prep + prop0 ----------------------------------
// Phase 1: r10 MFMA conv (LDS tile smemA, XOR swizzle). Offset planes (oc<16)
// stored directly. Phase 2: biased acc for all 24 oc -> LDS exchange buffer
// (stride 25 floats: conflict-free). Phase 3: stage initd + conf tiles into
// the dead remainder of smemA. Phase 4: threads re-map px-major and run
// prep (tanh/conf-sample/normalize -> aff planes) + prop step 0.
constexpr int CTILE_BYTES = 6 * 66 * 128;   // 50688
constexpr int CUNITS = CTILE_BYTES / 16;    // 3168
constexpr int EXCH_BYTES = 4 * 64 * 25 * 4; // 25600
constexpr int DT_OFF = EXCH_BYTES;          // disp tile offset in smemA
constexpr int CT_OFF = DT_OFF + TR * TC * 4;  // conf tile offset (+4928)
// CT_OFF + 4928 = 35456 <= 50688  ✓

__global__ __launch_bounds__(256) void conv_fused_kernel(
    const char* __restrict__ ws, const float* __restrict__ bias,
    const float* __restrict__ conf, const float* __restrict__ scale_p,
    const float* __restrict__ occm, const float* __restrict__ initd,
    float* __restrict__ out) {
  __shared__ __align__(16) char smemA[CTILE_BYTES];
  const int tid  = threadIdx.x;
  const int lane = tid & 63, wv = tid >> 6;
  const int lrow = lane & 15, lgrp = lane >> 4;
  const int x0 = blockIdx.x * 64;
  const int y0 = blockIdx.y * 4;
  const int bz = blockIdx.z;

  // ---- phase 1: stage NHWC tile, MFMA ----
  const char* Abase = ws + ((long)(bz * HP + y0) * WPAD + x0) * 128;
#pragma unroll
  for (int it = 0; it < 13; ++it) {
    int u = it * 256 + tid;
    if (u < CUNITS) {
      int pxl = u >> 3, j = u & 7;
      int r = pxl / 66, col = pxl - r * 66;
      uint4 v = *reinterpret_cast<const uint4*>(
          Abase + ((long)r * WPAD + col) * 128 + j * 16);
      int ldsb = pxl * 128 + ((j ^ (col & 7)) << 4);
      *reinterpret_cast<uint4*>(smemA + ldsb) = v;
    }
  }
  __syncthreads();

  const char* Wb = ws + WOFF + (long)lrow * 128 + lgrp * 16;

  f32x4 acc[4][2];
#pragma unroll
  for (int h = 0; h < 4; ++h)
#pragma unroll
    for (int nt = 0; nt < 2; ++nt) acc[h][nt] = (f32x4){0.f, 0.f, 0.f, 0.f};

#pragma unroll
  for (int tap = 0; tap < 9; ++tap) {
    const int dy = tap / 3, dx = tap - dy * 3;
    const char* Wt = Wb + tap * 4096;
#pragma unroll
    for (int ks = 0; ks < 2; ++ks) {
      bf16x8 wf0 = *reinterpret_cast<const bf16x8*>(Wt + ks * 64);
      bf16x8 wf1 = *reinterpret_cast<const bf16x8*>(Wt + 2048 + ks * 64);
#pragma unroll
      for (int h = 0; h < 4; ++h) {
        const int colc = lrow + dx + h * 16;
        int abyte = ((wv + dy) * 66 + colc) * 128 +
                    ((((ks << 2) + lgrp) ^ (colc & 7)) << 4);
        bf16x8 af = *reinterpret_cast<const bf16x8*>(smemA + abyte);
        acc[h][0] = __builtin_amdgcn_mfma_f32_16x16x32_bf16(af, wf0, acc[h][0], 0, 0, 0);
        acc[h][1] = __builtin_amdgcn_mfma_f32_16x16x32_bf16(af, wf1, acc[h][1], 0, 0, 0);
      }
    }
  }
  __syncthreads();   // all waves done reading smemA -> safe to reuse

  // ---- phase 2: offset-plane stores + exchange buffer writes ----
  float* exch = reinterpret_cast<float*>(smemA);
  {
    const int y = y0 + wv;
#pragma unroll
    for (int h = 0; h < 4; ++h) {
      const int xx = x0 + h * 16 + lgrp * 4;       // global px of v[0]
      const int lpx = h * 16 + lgrp * 4;           // block-local px
#pragma unroll
      for (int nt = 0; nt < 2; ++nt) {
        int oc = nt * 16 + lrow;
        if (oc >= 24) continue;
        float bv = bias[oc];
        f32x4 v = acc[h][nt];
        // exchange: all 24 channels, biased
#pragma unroll
        for (int j = 0; j < 4; ++j)
          exch[(wv * 64 + lpx + j) * 25 + oc] = v[j] + bv;
        if (oc < 16) {
          int n = oc >> 1, cd = oc & 1;
          int mm = (n < IDXR) ? n : n + 1;
          long dst = OUT2 + (long)(bz * 18 + 2 * mm + cd) * HW;
          float4 st = make_float4(v[0] + bv, v[1] + bv, v[2] + bv, v[3] + bv);
          *reinterpret_cast<float4*>(&out[dst + (long)y * Wc + xx]) = st;
        }
      }
    }
  }
  __syncthreads();

  // ---- phase 3: stage initd + conf tiles into dead LDS ----
  float (*dtile)[TC] = reinterpret_cast<float (*)[TC]>(smemA + DT_OFF);
  float (*ctile)[TC] = reinterpret_cast<float (*)[TC]>(smemA + CT_OFF);
  const float* db    = initd + (long)bz * HW;
  const float* confb = conf  + (long)bz * HW;
  stage_tile(dtile, db,    y0, x0, tid);
  stage_tile(ctile, confb, y0, x0, tid);
  __syncthreads();

  // ---- phase 4: px-major prep + prop0 ----
  const int row = tid >> 6, px = tid & 63;
  const int y = y0 + row, x = x0 + px;
  long rem = (long)y * Wc + x;
  long p = (long)bz * HW + rem;

  float ch[24];
#pragma unroll
  for (int j = 0; j < 24; ++j) ch[j] = exch[(row * 64 + px) * 25 + j];

  const float inv_scale = 1.f / (scale_p[0] + 1e-8f);
  float* off  = out + OUT2 + (long)bz * 18 * HW + rem;
  float* affp = out + OUT3 + (long)bz * 9  * HW + rem;

  float affr[9], oyr[9], oxr[9];
  float asum = 0.f;
#pragma unroll
  for (int m = 0; m < 8; m++) {
    int n = (m < IDXR) ? m : m + 1;
    float oy  = ch[2 * m];
    float ox  = ch[2 * m + 1];
    float raw = ch[16 + m];
    float avv = tanhf(raw) * inv_scale;
    float cs  = bilin_tile(ctile, confb, y0, x0, (float)y + oy, (float)x + ox);
    affr[n] = avv * cs;
    oyr[n] = oy; oxr[n] = ox;
    asum += fabsf(affr[n]);
  }
  float s = fmaxf(asum + 1e-5f, 1.0f);
  float inv_s = 1.f / s;
  float total = 0.f;
#pragma unroll
  for (int m = 0; m < 8; m++) {
    int n = (m < IDXR) ? m : m + 1;
    affr[n] *= inv_s; total += affr[n];
  }
  affr[IDXR] = 1.f - total;
  oyr[IDXR] = 0.f; oxr[IDXR] = 0.f;
#pragma unroll
  for (int n = 0; n < 9; n++) affp[(long)n * HW] = affr[n];
  off[(long)(2 * IDXR) * HW]     = 0.f;
  off[(long)(2 * IDXR + 1) * HW] = 0.f;
  if (p == 0) out[OUT4] = scale_p[0];

  // prop step 0 (from initial_disp via LDS tile)
  float occv  = occm[p];
  float initv = db[rem];
  float acc0 = 0.f;
#pragma unroll
  for (int k = 0; k < 9; k++) {
    float sy = (float)(y + k / 3 - 1) + oyr[k];
    float sx = (float)(x + k % 3 - 1) + oxr[k];
    acc0 = fmaf(affr[k], bilin_tile(dtile, db, y0, x0, sy, sx), acc0);
  }
  acc0 = fmaxf(acc0, 0.f);
  out[OUT1 + p] = (1.f - occv) * acc0 + occv * initv;
}

// ---------------- propagation steps 1..5 (tiled disp, plane state) -----------
__global__ __launch_bounds__(256) void prop_tile_kernel(
    const float* __restrict__ dispPrev,
    const float* __restrict__ occ, const float* __restrict__ initd,
    float* __restrict__ out, int t) {
  __shared__ float tile[TR][TC];
  const int tid = threadIdx.x;
  const int x0 = blockIdx.x * PC;
  const int y0 = blockIdx.y * PR;
  const int b  = blockIdx.z;
  const float* db = dispPrev + (long)b * HW;
  stage_tile(tile, db, y0, x0, tid);
  __syncthreads();

  const int y = y0 + (tid >> 6);
  const int x = x0 + (tid & 63);
  long rem = (long)y * Wc + x;
  long p = (long)b * HW + rem;

  const float* off  = out + OUT2 + (long)b * 18 * HW + rem;
  const float* affp = out + OUT3 + (long)b * 9  * HW + rem;

  float acc = 0.f;
#pragma unroll
  for (int k = 0; k < 9; k++) {
    float oy = off[(long)(2 * k) * HW];
    float ox = off[(long)(2 * k + 1) * HW];
    float av = affp[(long)k * HW];
    float sy = (float)(y + k / 3 - 1) + oy;
    float sx = (float)(x + k % 3 - 1) + ox;
    acc = fmaf(av, bilin_tile(tile, db, y0, x0, sy, sx), acc);
  }
  acc = fmaxf(acc, 0.f);
  float o = occ[p];
  float res = (1.f - o) * acc + o * initd[p];
  out[OUT1 + (long)t * BHW + p] = res;
  if (t == PROP - 1) out[OUT0 + p] = res;
}

// ================= legacy fallback path (ws too small) =======================
constexpr int TY = 8, TX = 32;
constexpr int AR = TY + 2, AC = TX + 2;
constexpr int A_BYTES = AR * AC * CGc * 2;
constexpr int W_BYTES = 9 * 32 * 32 * 2;

__global__ __launch_bounds__(256) void conv_mfma_kernel(
    const float* __restrict__ g, const float* __restrict__ wsrc,
    const float* __restrict__ bias, float* __restrict__ out) {
  __shared__ __align__(16) char smemA[A_BYTES];
  __shared__ __align__(16) char smemW[W_BYTES];
  const int tid = threadIdx.x;
  const int x0 = blockIdx.x * TX;
  const int y0 = blockIdx.y * TY;
  const int bz = blockIdx.z;
  const float* gb = g + (long)bz * CGc * HW;
  for (int w = tid; w < AR * AC * 32; w += 256) {
    int c  = w % AC;
    int t2 = w / AC;
    int icp = t2 & 31;
    int r   = t2 >> 5;
    int y = y0 + r - 1, x = x0 + c - 1;
    float v0 = 0.f, v1 = 0.f;
    if (y >= 0 && y < Hc && x >= 0 && x < Wc) {
      const float* p = gb + (long)(2 * icp) * HW + (long)y * Wc + x;
      v0 = p[0]; v1 = p[HW];
    }
    unsigned int pk = (unsigned int)f2bf(v0) | ((unsigned int)f2bf(v1) << 16);
    int byte = (r * AC + c) * 128 + icp * 4;
    byte ^= (c & 7) << 4;
    *reinterpret_cast<unsigned int*>(smemA + byte) = pk;
  }
  auto stageW = [&](int hs) {
    for (int idx = tid; idx < 24 * 32 * 9; idx += 256) {
      int oc  = idx / 288;
      int r1  = idx - oc * 288;
      int icl = r1 / 9;
      int tap = r1 - icl * 9;
      float f = wsrc[idx + 288 * (oc + hs)];
      int byte = (tap * 32 + oc) * 64 + icl * 2;
      byte ^= (oc & 7) << 4;
      *reinterpret_cast<unsigned short*>(smemW + byte) = f2bf(f);
    }
  };
  stageW(0);
  __syncthreads();
  const int wid  = tid >> 6;
  const int lane = tid & 63;
  const int lrow = lane & 15;
  const int lgrp = lane >> 4;
  f32x4 acc[4][2];
#pragma unroll
  for (int m = 0; m < 4; m++)
#pragma unroll
    for (int nt = 0; nt < 2; nt++) acc[m][nt] = (f32x4){0.f, 0.f, 0.f, 0.f};
  for (int ks = 0; ks < 2; ++ks) {
    if (ks) { __syncthreads(); stageW(1); __syncthreads(); }
#pragma unroll
    for (int tap = 0; tap < 9; ++tap) {
      const int dy = tap / 3, dx = tap - dy * 3;
      int bb = (tap * 32 + lrow) * 64 + lgrp * 16;
      int bbyte0 = bb ^ ((lrow & 7) << 4);
      int bbyte1 = (bb + 16 * 64) ^ ((lrow & 7) << 4);
      bf16x8 bf0 = *reinterpret_cast<const bf16x8*>(smemW + bbyte0);
      bf16x8 bf1 = *reinterpret_cast<const bf16x8*>(smemW + bbyte1);
#pragma unroll
      for (int dr = 0; dr < 2; ++dr) {
        const int rin = 2 * wid + dr + dy;
#pragma unroll
        for (int h = 0; h < 2; ++h) {
          const int cin = h * 16 + lrow + dx;
          int abyte = ((rin * AC + cin) * 128 + ks * 64 + lgrp * 16) ^ ((cin & 7) << 4);
          bf16x8 af = *reinterpret_cast<const bf16x8*>(smemA + abyte);
          acc[dr * 2 + h][0] = __builtin_amdgcn_mfma_f32_16x16x32_bf16(af, bf0, acc[dr * 2 + h][0], 0, 0, 0);
          acc[dr * 2 + h][1] = __builtin_amdgcn_mfma_f32_16x16x32_bf16(af, bf1, acc[dr * 2 + h][1], 0, 0, 0);
        }
      }
    }
  }
#pragma unroll
  for (int dr = 0; dr < 2; ++dr) {
    const int yy = y0 + 2 * wid + dr;
#pragma unroll
    for (int h = 0; h < 2; ++h) {
      const int xx = x0 + h * 16 + lgrp * 4;
#pragma unroll
      for (int nt = 0; nt < 2; ++nt) {
        int oc = nt * 16 + lrow;
        if (oc >= 24) continue;
        float bv = bias[oc];
        long dst;
        if (oc < 16) {
          int n = oc >> 1, cd = oc & 1;
          int mm = (n < IDXR) ? n : n + 1;
          dst = OUT2 + (long)(bz * 18 + 2 * mm + cd) * HW;
        } else {
          int i2 = oc - 16;
          int mm = (i2 < IDXR) ? i2 : i2 + 1;
          dst = OUT3 + (long)(bz * 9 + mm) * HW;
        }
        f32x4 v = acc[dr * 2 + h][nt];
        float4 st = make_float4(v[0] + bv, v[1] + bv, v[2] + bv, v[3] + bv);
        *reinterpret_cast<float4*>(&out[dst + (long)yy * Wc + xx]) = st;
      }
    }
  }
}

__global__ __launch_bounds__(256) void prep_kernel(
    const float* __restrict__ conf, const float* __restrict__ scale_p,
    float* __restrict__ out) {
  long p = (long)blockIdx.x * 256 + threadIdx.x;
  if (p >= BHW) return;
  int b = (int)(p / HW);
  long rem = p - (long)b * HW;
  int y = (int)(rem / Wc);
  int x = (int)(rem - (long)y * Wc);
  const float inv_scale = 1.f / (scale_p[0] + 1e-8f);
  const float* confb = conf + (long)b * HW;
  float* off  = out + OUT2 + (long)b * 18 * HW + rem;
  float* affp = out + OUT3 + (long)b * 9  * HW + rem;
  float a[8];
  float asum = 0.f;
#pragma unroll
  for (int m = 0; m < 8; m++) {
    int n = (m < IDXR) ? m : m + 1;
    float oy  = off[(long)(2 * n) * HW];
    float ox  = off[(long)(2 * n + 1) * HW];
    float raw = affp[(long)n * HW];
    float av  = tanhf(raw) * inv_scale;
    float cs  = bilin(confb, (float)y + oy, (float)x + ox);
    a[m] = av * cs;
    asum += fabsf(a[m]);
  }
  float s = fmaxf(asum + 1e-5f, 1.0f);
  float inv_s = 1.f / s;
  float total = 0.f;
#pragma unroll
  for (int m = 0; m < 8; m++) { a[m] *= inv_s; total += a[m]; }
  float aref = 1.f - total;
#pragma unroll
  for (int m = 0; m < 8; m++) {
    int n = (m < IDXR) ? m : m + 1;
    affp[(long)n * HW] = a[m];
  }
  affp[(long)IDXR * HW] = aref;
  off[(long)(2 * IDXR) * HW]     = 0.f;
  off[(long)(2 * IDXR + 1) * HW] = 0.f;
  if (p == 0) out[OUT4] = scale_p[0];
}

__global__ __launch_bounds__(256) void prop_kernel(
    const float* __restrict__ dispPrev,
    const float* __restrict__ occ, const float* __restrict__ initd,
    float* __restrict__ out, int t) {
  long p = (long)blockIdx.x * 256 + threadIdx.x;
  if (p >= BHW) return;
  int b = (int)(p / HW);
  long rem = p - (long)b * HW;
  int y = (int)(rem / Wc);
  int x = (int)(rem - (long)y * Wc);
  const float* off  = out + OUT2 + (long)b * 18 * HW + rem;
  const float* affp = out + OUT3 + (long)b * 9  * HW + rem;
  const float* db   = dispPrev + (long)b * HW;
  float acc = 0.f;
#pragma unroll
  for (int k = 0; k < 9; k++) {
    float oy = off[(long)(2 * k) * HW];
    float ox = off[(long)(2 * k + 1) * HW];
    float av = affp[(long)k * HW];
    float sy = (float)(y + k / 3 - 1) + oy;
    float sx = (float)(x + k % 3 - 1) + ox;
    acc = fmaf(av, bilin(db, sy, sx), acc);
  }
  acc = fmaxf(acc, 0.f);
  float o = occ[p];
  float res = (1.f - o) * acc + o * initd[p];
  out[OUT1 + (long)t * BHW + p] = res;
  if (t == PROP - 1) out[OUT0 + p] = res;
}

extern "C" void kernel_launch(void* const* d_in, const int* in_sizes, int n_in,
                              void* d_out, int out_size, void* d_ws, size_t ws_size,
                              hipStream_t stream) {
  const float* initd = (const float*)d_in[0];
  const float* occ   = (const float*)d_in[1];
  const float* conf  = (const float*)d_in[2];
  const float* guid  = (const float*)d_in[3];
  const float* cw    = (const float*)d_in[4];
  const float* cb    = (const float*)d_in[5];
  const float* csc   = (const float*)d_in[6];
  float* out = (float*)d_out;
  int nblk = (int)((BHW + 255) / 256);  // 2280

  if (ws_size >= (size_t)WS_NEED) {
    char* ws = (char*)d_ws;
    nhwc_kernel<<<dim3(Wc / 64, Hc, Bc), 256, 0, stream>>>(guid, ws);
    border_kernel<<<(Bc * (2 * WPAD + 2 * (HP - 2)) + 255) / 256, 256, 0, stream>>>(ws);
    wconv_kernel<<<72, 256, 0, stream>>>(cw, ws);

    dim3 pgrid(Wc / PC, Hc / PR, Bc);  // (19, 60, 2)
    conv_fused_kernel<<<pgrid, 256, 0, stream>>>(ws, cb, conf, csc, occ, initd, out);
    for (int t = 1; t < PROP; t++) {
      const float* dp = out + OUT1 + (long)(t - 1) * BHW;
      prop_tile_kernel<<<pgrid, 256, 0, stream>>>(dp, occ, initd, out, t);
    }
  } else {
    conv_mfma_kernel<<<dim3(Wc / TX, Hc / TY, Bc), 256, 0, stream>>>(guid, cw, cb, out);
    prep_kernel<<<nblk, 256, 0, stream>>>(conf, csc, out);
    for (int t = 0; t < PROP; t++) {
      const float* dp = (t == 0) ? initd : (out + OUT1 + (long)(t - 1) * BHW);
      prop_kernel<<<nblk, 256, 0, stream>>>(dp, occ, initd, out, t);
    }
  }
}

// Round 17
// 201.328 us; speedup vs baseline: 1.1998x; 1.1090x over previous
//
#include <hip/hip_runtime.h>
#include <hip/hip_bf16.h>
#include <math.h>
#include <string.h>

typedef __attribute__((ext_vector_type(8))) short bf16x8;
typedef __attribute__((ext_vector_type(4))) float f32x4;

// Problem constants
constexpr int Bc = 2, CGc = 64, Hc = 240, Wc = 1216;
constexpr int IDXR = 4, PROP = 6;
constexpr long HW  = (long)Hc * Wc;      // 291840
constexpr long BHW = (long)Bc * HW;      // 583680

// d_out layout (floats)
constexpr long OUT0 = 0;
constexpr long OUT1 = BHW;
constexpr long OUT2 = BHW * 7;
constexpr long OUT3 = OUT2 + (long)Bc * 18 * HW;
constexpr long OUT4 = OUT3 + (long)Bc * 9 * HW;

// ---- padded NHWC bf16 guidance in ws: [b][py 0..241][px 0..1217][ic 0..63] --
constexpr int HP = Hc + 2, WPAD = Wc + 2;            // 242 x 1218
constexpr long APXB   = (long)HP * WPAD;
constexpr long A_TOT  = (long)Bc * APXB * 128;       // 75.5 MB
constexpr long WOFF   = A_TOT;
constexpr long WS_NEED = WOFF + (long)9 * 32 * 128;
// f16 prop-state table (overlaps NHWC region, dead after conv_fused; written
// by prop step 1, read by steps 2..5): uint4 tab4[4][BHW] = 37.4 MB < A_TOT.
// halves 0-8 aff, 9-17 oy, 18-26 ox, 27 pad; u[14]=occ f32, u[15]=init f32.

// prop tiling
constexpr int PR = 4, PC = 64, HLO = 6;
constexpr int TR = PR + 2 * HLO;        // 16 rows
constexpr int TC = PC + 2 * HLO + 1;    // 77 cols

__device__ __forceinline__ unsigned short f2bf(float f) {
  __hip_bfloat16 h = __float2bfloat16(f);
  return __builtin_bit_cast(unsigned short, h);
}
__device__ __forceinline__ unsigned short f2h(float f) {
  _Float16 h = (_Float16)f;
  return __builtin_bit_cast(unsigned short, h);
}
__device__ __forceinline__ float h2f(unsigned short u) {
  return (float)__builtin_bit_cast(_Float16, u);
}

// horizontal pair load with zero padding; interior = one 8B load
__device__ __forceinline__ void row2(const float* __restrict__ img, int yy, int x0,
                                     float& a, float& b) {
  if (yy >= 0 && yy < Hc) {
    if (x0 >= 0 && x0 < Wc - 1) {
      float2 v;
      __builtin_memcpy(&v, img + (long)yy * Wc + x0, 8);
      a = v.x; b = v.y;
    } else {
      a = (x0 >= 0 && x0 < Wc)         ? img[(long)yy * Wc + x0]     : 0.f;
      b = (x0 + 1 >= 0 && x0 + 1 < Wc) ? img[(long)yy * Wc + x0 + 1] : 0.f;
    }
  } else { a = 0.f; b = 0.f; }
}

__device__ __forceinline__ float bilin(const float* __restrict__ img, float y, float x) {
  float y0f = floorf(y), x0f = floorf(x);
  int y0 = (int)y0f, x0 = (int)x0f;
  float wy = y - y0f, wx = x - x0f;
  float v00, v01, v10, v11;
  row2(img, y0,     x0, v00, v01);
  row2(img, y0 + 1, x0, v10, v11);
  float top = v00 + wx * (v01 - v00);
  float bot = v10 + wx * (v11 - v10);
  return top + wy * (bot - top);
}

// bilinear out of a staged tile with global fallback
__device__ __forceinline__ float bilin_tile(
    const float (*tile)[TC], const float* __restrict__ db,
    int y0, int x0, float sy, float sx) {
  float yf = floorf(sy), xf = floorf(sx);
  int iy = (int)yf, ix = (int)xf;
  float wy = sy - yf, wx = sx - xf;
  if (iy >= y0 - HLO && iy + 1 <= y0 + PR - 1 + HLO &&
      ix >= x0 - HLO && ix + 1 <= x0 + PC - 1 + HLO) {
    int ly = iy - (y0 - HLO), lx = ix - (x0 - HLO);
    float v00 = tile[ly][lx],     v01 = tile[ly][lx + 1];
    float v10 = tile[ly + 1][lx], v11 = tile[ly + 1][lx + 1];
    float top = v00 + wx * (v01 - v00);
    float bot = v10 + wx * (v11 - v10);
    return top + wy * (bot - top);
  }
  return bilin(db, sy, sx);
}

__device__ __forceinline__ void stage_tile(
    float (*tile)[TC], const float* __restrict__ db, int y0, int x0, int tid) {
  for (int i = tid; i < TR * TC; i += 256) {
    int rr = i / TC, cc = i - rr * TC;
    int gy = y0 - HLO + rr, gx = x0 - HLO + cc;
    tile[rr][cc] = (gy >= 0 && gy < Hc && gx >= 0 && gx < Wc)
                       ? db[(long)gy * Wc + gx] : 0.f;
  }
}

// ---------------- NCHW f32 -> padded NHWC bf16 (tiled transpose) -------------
__global__ __launch_bounds__(256) void nhwc_kernel(
    const float* __restrict__ g, char* __restrict__ ws) {
  __shared__ __align__(16) char tileb[64 * 132];
  const int tid = threadIdx.x;
  const int x0 = blockIdx.x * 64;
  const int y  = blockIdx.y;
  const int bz = blockIdx.z;
  const float* gb = g + (long)bz * CGc * HW + (long)y * Wc + x0;
  const int px = tid & 63, wv = tid >> 6;
#pragma unroll
  for (int k = 0; k < 16; ++k) {
    int ic = k * 4 + wv;
    float v = gb[(long)ic * HW + px];
    *reinterpret_cast<unsigned short*>(tileb + px * 132 + ic * 2) = f2bf(v);
  }
  __syncthreads();
  const int opx = tid >> 2, q = tid & 3;
  unsigned int u[8];
#pragma unroll
  for (int j = 0; j < 8; ++j)
    u[j] = *reinterpret_cast<unsigned int*>(tileb + opx * 132 + q * 32 + j * 4);
  char* dst = ws + ((long)(bz * HP + y + 1) * WPAD + x0 + 1 + opx) * 128 + q * 32;
  reinterpret_cast<uint4*>(dst)[0] = make_uint4(u[0], u[1], u[2], u[3]);
  reinterpret_cast<uint4*>(dst)[1] = make_uint4(u[4], u[5], u[6], u[7]);
}

// ---------------- zero the pad border ---------------------------------------
__global__ __launch_bounds__(256) void border_kernel(char* __restrict__ ws) {
  constexpr int NB = 2 * WPAD + 2 * (HP - 2);
  long i = (long)blockIdx.x * 256 + threadIdx.x;
  if (i >= (long)Bc * NB) return;
  int bz = (int)(i / NB);
  int r  = (int)(i - (long)bz * NB);
  int py, px;
  if (r < WPAD)            { py = 0;      px = r; }
  else if (r < 2 * WPAD)   { py = HP - 1; px = r - WPAD; }
  else { int qq = r - 2 * WPAD; py = 1 + (qq >> 1); px = (qq & 1) ? (WPAD - 1) : 0; }
  char* p = ws + ((long)(bz * HP + py) * WPAD + px) * 128;
  uint4 z = make_uint4(0, 0, 0, 0);
#pragma unroll
  for (int j = 0; j < 8; ++j) reinterpret_cast<uint4*>(p)[j] = z;
}

// ---------------- W: OIHW f32 -> [tap9][oc32][ic64] bf16 (72 blocks) ---------
__global__ __launch_bounds__(256) void wconv_kernel(
    const float* __restrict__ w, char* __restrict__ ws) {
  char* wd = ws + WOFF;
  int idx = blockIdx.x * 256 + threadIdx.x;
  if (idx < 24 * 64 * 9) {
    int oc = idx / 576, r = idx - oc * 576;
    int ic = r / 9, tap = r - ic * 9;
    *reinterpret_cast<unsigned short*>(wd + tap * 4096 + oc * 128 + ic * 2) = f2bf(w[idx]);
  } else if (idx < 32 * 64 * 9) {
    int i2 = idx - 24 * 64 * 9;
    int oc = 24 + i2 / 576, r = i2 % 576;
    int ic = r / 9, tap = r % 9;
    *reinterpret_cast<unsigned short*>(wd + tap * 4096 + oc * 128 + ic * 2) = 0;
  }
}

// ---------------- fused conv + prep + prop0 ----------------------------------
constexpr int CTILE_BYTES = 6 * 66 * 128;   // 50688
constexpr int CUNITS = CTILE_BYTES / 16;    // 3168
constexpr int EXST = 26;                    // exch stride (2-way banks: free)
constexpr int EXCH_BYTES = 4 * 64 * EXST * 4; // 26624
constexpr int DT_OFF = EXCH_BYTES;
constexpr int CT_OFF = DT_OFF + TR * TC * 4;
// CT_OFF + 4928 = 36480 <= 50688 ✓

__global__ __launch_bounds__(256) void conv_fused_kernel(
    const char* __restrict__ ws, const float* __restrict__ bias,
    const float* __restrict__ conf, const float* __restrict__ scale_p,
    const float* __restrict__ occm, const float* __restrict__ initd,
    float* __restrict__ out) {
  __shared__ __align__(16) char smemA[CTILE_BYTES];
  const int tid  = threadIdx.x;
  const int lane = tid & 63, wv = tid >> 6;
  const int lrow = lane & 15, lgrp = lane >> 4;
  const int x0 = blockIdx.x * 64;
  const int y0 = blockIdx.y * 4;
  const int bz = blockIdx.z;

  // ---- phase 1: stage NHWC tile, MFMA ----
  const char* Abase = ws + ((long)(bz * HP + y0) * WPAD + x0) * 128;
#pragma unroll
  for (int it = 0; it < 13; ++it) {
    int u = it * 256 + tid;
    if (u < CUNITS) {
      int pxl = u >> 3, j = u & 7;
      int r = pxl / 66, col = pxl - r * 66;
      uint4 v = *reinterpret_cast<const uint4*>(
          Abase + ((long)r * WPAD + col) * 128 + j * 16);
      int ldsb = pxl * 128 + ((j ^ (col & 7)) << 4);
      *reinterpret_cast<uint4*>(smemA + ldsb) = v;
    }
  }
  __syncthreads();

  const char* Wb = ws + WOFF + (long)lrow * 128 + lgrp * 16;

  f32x4 acc[4][2];
#pragma unroll
  for (int h = 0; h < 4; ++h)
#pragma unroll
    for (int nt = 0; nt < 2; ++nt) acc[h][nt] = (f32x4){0.f, 0.f, 0.f, 0.f};

#pragma unroll
  for (int tap = 0; tap < 9; ++tap) {
    const int dy = tap / 3, dx = tap - dy * 3;
    const char* Wt = Wb + tap * 4096;
#pragma unroll
    for (int ks = 0; ks < 2; ++ks) {
      bf16x8 wf0 = *reinterpret_cast<const bf16x8*>(Wt + ks * 64);
      bf16x8 wf1 = *reinterpret_cast<const bf16x8*>(Wt + 2048 + ks * 64);
#pragma unroll
      for (int h = 0; h < 4; ++h) {
        const int colc = lrow + dx + h * 16;
        int abyte = ((wv + dy) * 66 + colc) * 128 +
                    ((((ks << 2) + lgrp) ^ (colc & 7)) << 4);
        bf16x8 af = *reinterpret_cast<const bf16x8*>(smemA + abyte);
        acc[h][0] = __builtin_amdgcn_mfma_f32_16x16x32_bf16(af, wf0, acc[h][0], 0, 0, 0);
        acc[h][1] = __builtin_amdgcn_mfma_f32_16x16x32_bf16(af, wf1, acc[h][1], 0, 0, 0);
      }
    }
  }
  __syncthreads();   // safe to reuse smemA

  // ---- phase 2: offset-plane stores + exchange buffer writes ----
  float* exch = reinterpret_cast<float*>(smemA);
  {
    const int y = y0 + wv;
#pragma unroll
    for (int h = 0; h < 4; ++h) {
      const int xx = x0 + h * 16 + lgrp * 4;
      const int lpx = h * 16 + lgrp * 4;
#pragma unroll
      for (int nt = 0; nt < 2; ++nt) {
        int oc = nt * 16 + lrow;
        if (oc >= 24) continue;
        float bv = bias[oc];
        f32x4 v = acc[h][nt];
#pragma unroll
        for (int j = 0; j < 4; ++j)
          exch[(wv * 64 + lpx + j) * EXST + oc] = v[j] + bv;
        if (oc < 16) {
          int n = oc >> 1, cd = oc & 1;
          int mm = (n < IDXR) ? n : n + 1;
          long dst = OUT2 + (long)(bz * 18 + 2 * mm + cd) * HW;
          float4 st = make_float4(v[0] + bv, v[1] + bv, v[2] + bv, v[3] + bv);
          *reinterpret_cast<float4*>(&out[dst + (long)y * Wc + xx]) = st;
        }
      }
    }
  }
  __syncthreads();

  // ---- phase 3: stage initd + conf tiles into dead LDS ----
  float (*dtile)[TC] = reinterpret_cast<float (*)[TC]>(smemA + DT_OFF);
  float (*ctile)[TC] = reinterpret_cast<float (*)[TC]>(smemA + CT_OFF);
  const float* db    = initd + (long)bz * HW;
  const float* confb = conf  + (long)bz * HW;
  stage_tile(dtile, db,    y0, x0, tid);
  stage_tile(ctile, confb, y0, x0, tid);
  __syncthreads();

  // ---- phase 4: px-major prep + prop0 ----
  const int row = tid >> 6, px = tid & 63;
  const int y = y0 + row, x = x0 + px;
  long rem = (long)y * Wc + x;
  long p = (long)bz * HW + rem;

  float ch[24];
#pragma unroll
  for (int j = 0; j < 24; ++j) ch[j] = exch[(row * 64 + px) * EXST + j];

  const float inv_scale = 1.f / (scale_p[0] + 1e-8f);
  float* off  = out + OUT2 + (long)bz * 18 * HW + rem;
  float* affp = out + OUT3 + (long)bz * 9  * HW + rem;

  float affr[9], oyr[9], oxr[9];
  float asum = 0.f;
#pragma unroll
  for (int m = 0; m < 8; m++) {
    int n = (m < IDXR) ? m : m + 1;
    float oy  = ch[2 * m];
    float ox  = ch[2 * m + 1];
    float raw = ch[16 + m];
    float avv = tanhf(raw) * inv_scale;
    float cs  = bilin_tile(ctile, confb, y0, x0, (float)y + oy, (float)x + ox);
    affr[n] = avv * cs;
    oyr[n] = oy; oxr[n] = ox;
    asum += fabsf(affr[n]);
  }
  float s = fmaxf(asum + 1e-5f, 1.0f);
  float inv_s = 1.f / s;
  float total = 0.f;
#pragma unroll
  for (int m = 0; m < 8; m++) {
    int n = (m < IDXR) ? m : m + 1;
    affr[n] *= inv_s; total += affr[n];
  }
  affr[IDXR] = 1.f - total;
  oyr[IDXR] = 0.f; oxr[IDXR] = 0.f;
#pragma unroll
  for (int n = 0; n < 9; n++) affp[(long)n * HW] = affr[n];
  off[(long)(2 * IDXR) * HW]     = 0.f;
  off[(long)(2 * IDXR + 1) * HW] = 0.f;
  if (p == 0) out[OUT4] = scale_p[0];

  // prop step 0
  float occv  = occm[p];
  float initv = db[rem];
  float acc0 = 0.f;
#pragma unroll
  for (int k = 0; k < 9; k++) {
    float sy = (float)(y + k / 3 - 1) + oyr[k];
    float sx = (float)(x + k % 3 - 1) + oxr[k];
    acc0 = fmaf(affr[k], bilin_tile(dtile, db, y0, x0, sy, sx), acc0);
  }
  acc0 = fmaxf(acc0, 0.f);
  out[OUT1 + p] = (1.f - occv) * acc0 + occv * initv;
}

// ---------------- prop step 1: plane-read prop + f16 table write -------------
__global__ __launch_bounds__(256) void prop_tab1_kernel(
    const float* __restrict__ dispPrev,
    const float* __restrict__ occ, const float* __restrict__ initd,
    float* __restrict__ out, uint4* __restrict__ tab4) {
  __shared__ float tile[TR][TC];
  const int tid = threadIdx.x;
  const int x0 = blockIdx.x * PC;
  const int y0 = blockIdx.y * PR;
  const int b  = blockIdx.z;
  const float* db = dispPrev + (long)b * HW;
  stage_tile(tile, db, y0, x0, tid);
  __syncthreads();

  const int y = y0 + (tid >> 6);
  const int x = x0 + (tid & 63);
  long rem = (long)y * Wc + x;
  long p = (long)b * HW + rem;

  const float* off  = out + OUT2 + (long)b * 18 * HW + rem;
  const float* affp = out + OUT3 + (long)b * 9  * HW + rem;

  float affv[9], oyv[9], oxv[9];
#pragma unroll
  for (int k = 0; k < 9; k++) {
    oyv[k]  = off[(long)(2 * k) * HW];
    oxv[k]  = off[(long)(2 * k + 1) * HW];
    affv[k] = affp[(long)k * HW];
  }
  float occv  = occ[p];
  float initv = initd[p];

  float acc = 0.f;
#pragma unroll
  for (int k = 0; k < 9; k++) {
    float sy = (float)(y + k / 3 - 1) + oyv[k];
    float sx = (float)(x + k % 3 - 1) + oxv[k];
    acc = fmaf(affv[k], bilin_tile(tile, db, y0, x0, sy, sx), acc);
  }
  acc = fmaxf(acc, 0.f);
  float res = (1.f - occv) * acc + occv * initv;
  out[OUT1 + (long)1 * BHW + p] = res;

  // pack f16 state table
  unsigned short hs[28];
#pragma unroll
  for (int k = 0; k < 9; k++) {
    hs[k] = f2h(affv[k]); hs[9 + k] = f2h(oyv[k]); hs[18 + k] = f2h(oxv[k]);
  }
  hs[27] = 0;
  unsigned u[16];
#pragma unroll
  for (int i = 0; i < 14; i++)
    u[i] = (unsigned)hs[2 * i] | ((unsigned)hs[2 * i + 1] << 16);
  u[14] = __builtin_bit_cast(unsigned, occv);
  u[15] = __builtin_bit_cast(unsigned, initv);
#pragma unroll
  for (int g = 0; g < 4; g++)
    tab4[(long)g * BHW + p] = make_uint4(u[4 * g], u[4 * g + 1], u[4 * g + 2], u[4 * g + 3]);
}

// ---------------- prop steps 2..5: f16 table read -----------------------------
__global__ __launch_bounds__(256) void prop_tabN_kernel(
    const float* __restrict__ dispPrev, const uint4* __restrict__ tab4,
    float* __restrict__ out, int t) {
  __shared__ float tile[TR][TC];
  const int tid = threadIdx.x;
  const int x0 = blockIdx.x * PC;
  const int y0 = blockIdx.y * PR;
  const int b  = blockIdx.z;
  const float* db = dispPrev + (long)b * HW;
  stage_tile(tile, db, y0, x0, tid);
  __syncthreads();

  const int y = y0 + (tid >> 6);
  const int x = x0 + (tid & 63);
  long rem = (long)y * Wc + x;
  long p = (long)b * HW + rem;

  unsigned u[16];
#pragma unroll
  for (int g = 0; g < 4; g++) {
    uint4 q = tab4[(long)g * BHW + p];
    u[4 * g] = q.x; u[4 * g + 1] = q.y; u[4 * g + 2] = q.z; u[4 * g + 3] = q.w;
  }
  float fl[27];
#pragma unroll
  for (int i = 0; i < 27; i++) {
    unsigned w0 = u[i >> 1];
    fl[i] = h2f((unsigned short)((i & 1) ? (w0 >> 16) : (w0 & 0xffff)));
  }
  float occv  = __builtin_bit_cast(float, u[14]);
  float initv = __builtin_bit_cast(float, u[15]);

  float acc = 0.f;
#pragma unroll
  for (int k = 0; k < 9; k++) {
    float sy = (float)(y + k / 3 - 1) + fl[9 + k];
    float sx = (float)(x + k % 3 - 1) + fl[18 + k];
    acc = fmaf(fl[k], bilin_tile(tile, db, y0, x0, sy, sx), acc);
  }
  acc = fmaxf(acc, 0.f);
  float res = (1.f - occv) * acc + occv * initv;
  out[OUT1 + (long)t * BHW + p] = res;
  if (t == PROP - 1) out[OUT0 + p] = res;
}

// ================= legacy fallback path (ws too small) =======================
constexpr int TY = 8, TX = 32;
constexpr int AR = TY + 2, AC = TX + 2;
constexpr int A_BYTES = AR * AC * CGc * 2;
constexpr int W_BYTES = 9 * 32 * 32 * 2;

__global__ __launch_bounds__(256) void conv_mfma_kernel(
    const float* __restrict__ g, const float* __restrict__ wsrc,
    const float* __restrict__ bias, float* __restrict__ out) {
  __shared__ __align__(16) char smemA[A_BYTES];
  __shared__ __align__(16) char smemW[W_BYTES];
  const int tid = threadIdx.x;
  const int x0 = blockIdx.x * TX;
  const int y0 = blockIdx.y * TY;
  const int bz = blockIdx.z;
  const float* gb = g + (long)bz * CGc * HW;
  for (int w = tid; w < AR * AC * 32; w += 256) {
    int c  = w % AC;
    int t2 = w / AC;
    int icp = t2 & 31;
    int r   = t2 >> 5;
    int y = y0 + r - 1, x = x0 + c - 1;
    float v0 = 0.f, v1 = 0.f;
    if (y >= 0 && y < Hc && x >= 0 && x < Wc) {
      const float* p = gb + (long)(2 * icp) * HW + (long)y * Wc + x;
      v0 = p[0]; v1 = p[HW];
    }
    unsigned int pk = (unsigned int)f2bf(v0) | ((unsigned int)f2bf(v1) << 16);
    int byte = (r * AC + c) * 128 + icp * 4;
    byte ^= (c & 7) << 4;
    *reinterpret_cast<unsigned int*>(smemA + byte) = pk;
  }
  auto stageW = [&](int hs) {
    for (int idx = tid; idx < 24 * 32 * 9; idx += 256) {
      int oc  = idx / 288;
      int r1  = idx - oc * 288;
      int icl = r1 / 9;
      int tap = r1 - icl * 9;
      float f = wsrc[idx + 288 * (oc + hs)];
      int byte = (tap * 32 + oc) * 64 + icl * 2;
      byte ^= (oc & 7) << 4;
      *reinterpret_cast<unsigned short*>(smemW + byte) = f2bf(f);
    }
  };
  stageW(0);
  __syncthreads();
  const int wid  = tid >> 6;
  const int lane = tid & 63;
  const int lrow = lane & 15;
  const int lgrp = lane >> 4;
  f32x4 acc[4][2];
#pragma unroll
  for (int m = 0; m < 4; m++)
#pragma unroll
    for (int nt = 0; nt < 2; nt++) acc[m][nt] = (f32x4){0.f, 0.f, 0.f, 0.f};
  for (int ks = 0; ks < 2; ++ks) {
    if (ks) { __syncthreads(); stageW(1); __syncthreads(); }
#pragma unroll
    for (int tap = 0; tap < 9; ++tap) {
      const int dy = tap / 3, dx = tap - dy * 3;
      int bb = (tap * 32 + lrow) * 64 + lgrp * 16;
      int bbyte0 = bb ^ ((lrow & 7) << 4);
      int bbyte1 = (bb + 16 * 64) ^ ((lrow & 7) << 4);
      bf16x8 bf0 = *reinterpret_cast<const bf16x8*>(smemW + bbyte0);
      bf16x8 bf1 = *reinterpret_cast<const bf16x8*>(smemW + bbyte1);
#pragma unroll
      for (int dr = 0; dr < 2; ++dr) {
        const int rin = 2 * wid + dr + dy;
#pragma unroll
        for (int h = 0; h < 2; ++h) {
          const int cin = h * 16 + lrow + dx;
          int abyte = ((rin * AC + cin) * 128 + ks * 64 + lgrp * 16) ^ ((cin & 7) << 4);
          bf16x8 af = *reinterpret_cast<const bf16x8*>(smemA + abyte);
          acc[dr * 2 + h][0] = __builtin_amdgcn_mfma_f32_16x16x32_bf16(af, bf0, acc[dr * 2 + h][0], 0, 0, 0);
          acc[dr * 2 + h][1] = __builtin_amdgcn_mfma_f32_16x16x32_bf16(af, bf1, acc[dr * 2 + h][1], 0, 0, 0);
        }
      }
    }
  }
#pragma unroll
  for (int dr = 0; dr < 2; ++dr) {
    const int yy = y0 + 2 * wid + dr;
#pragma unroll
    for (int h = 0; h < 2; ++h) {
      const int xx = x0 + h * 16 + lgrp * 4;
#pragma unroll
      for (int nt = 0; nt < 2; ++nt) {
        int oc = nt * 16 + lrow;
        if (oc >= 24) continue;
        float bv = bias[oc];
        long dst;
        if (oc < 16) {
          int n = oc >> 1, cd = oc & 1;
          int mm = (n < IDXR) ? n : n + 1;
          dst = OUT2 + (long)(bz * 18 + 2 * mm + cd) * HW;
        } else {
          int i2 = oc - 16;
          int mm = (i2 < IDXR) ? i2 : i2 + 1;
          dst = OUT3 + (long)(bz * 9 + mm) * HW;
        }
        f32x4 v = acc[dr * 2 + h][nt];
        float4 st = make_float4(v[0] + bv, v[1] + bv, v[2] + bv, v[3] + bv);
        *reinterpret_cast<float4*>(&out[dst + (long)yy * Wc + xx]) = st;
      }
    }
  }
}

__global__ __launch_bounds__(256) void prep_kernel(
    const float* __restrict__ conf, const float* __restrict__ scale_p,
    float* __restrict__ out) {
  long p = (long)blockIdx.x * 256 + threadIdx.x;
  if (p >= BHW) return;
  int b = (int)(p / HW);
  long rem = p - (long)b * HW;
  int y = (int)(rem / Wc);
  int x = (int)(rem - (long)y * Wc);
  const float inv_scale = 1.f / (scale_p[0] + 1e-8f);
  const float* confb = conf + (long)b * HW;
  float* off  = out + OUT2 + (long)b * 18 * HW + rem;
  float* affp = out + OUT3 + (long)b * 9  * HW + rem;
  float a[8];
  float asum = 0.f;
#pragma unroll
  for (int m = 0; m < 8; m++) {
    int n = (m < IDXR) ? m : m + 1;
    float oy  = off[(long)(2 * n) * HW];
    float ox  = off[(long)(2 * n + 1) * HW];
    float raw = affp[(long)n * HW];
    float av  = tanhf(raw) * inv_scale;
    float cs  = bilin(confb, (float)y + oy, (float)x + ox);
    a[m] = av * cs;
    asum += fabsf(a[m]);
  }
  float s = fmaxf(asum + 1e-5f, 1.0f);
  float inv_s = 1.f / s;
  float total = 0.f;
#pragma unroll
  for (int m = 0; m < 8; m++) { a[m] *= inv_s; total += a[m]; }
  float aref = 1.f - total;
#pragma unroll
  for (int m = 0; m < 8; m++) {
    int n = (m < IDXR) ? m : m + 1;
    affp[(long)n * HW] = a[m];
  }
  affp[(long)IDXR * HW] = aref;
  off[(long)(2 * IDXR) * HW]     = 0.f;
  off[(long)(2 * IDXR + 1) * HW] = 0.f;
  if (p == 0) out[OUT4] = scale_p[0];
}

__global__ __launch_bounds__(256) void prop_kernel(
    const float* __restrict__ dispPrev,
    const float* __restrict__ occ, const float* __restrict__ initd,
    float* __restrict__ out, int t) {
  long p = (long)blockIdx.x * 256 + threadIdx.x;
  if (p >= BHW) return;
  int b = (int)(p / HW);
  long rem = p - (long)b * HW;
  int y = (int)(rem / Wc);
  int x = (int)(rem - (long)y * Wc);
  const float* off  = out + OUT2 + (long)b * 18 * HW + rem;
  const float* affp = out + OUT3 + (long)b * 9  * HW + rem;
  const float* db   = dispPrev + (long)b * HW;
  float acc = 0.f;
#pragma unroll
  for (int k = 0; k < 9; k++) {
    float oy = off[(long)(2 * k) * HW];
    float ox = off[(long)(2 * k + 1) * HW];
    float av = affp[(long)k * HW];
    float sy = (float)(y + k / 3 - 1) + oy;
    float sx = (float)(x + k % 3 - 1) + ox;
    acc = fmaf(av, bilin(db, sy, sx), acc);
  }
  acc = fmaxf(acc, 0.f);
  float o = occ[p];
  float res = (1.f - o) * acc + o * initd[p];
  out[OUT1 + (long)t * BHW + p] = res;
  if (t == PROP - 1) out[OUT0 + p] = res;
}

extern "C" void kernel_launch(void* const* d_in, const int* in_sizes, int n_in,
                              void* d_out, int out_size, void* d_ws, size_t ws_size,
                              hipStream_t stream) {
  const float* initd = (const float*)d_in[0];
  const float* occ   = (const float*)d_in[1];
  const float* conf  = (const float*)d_in[2];
  const float* guid  = (const float*)d_in[3];
  const float* cw    = (const float*)d_in[4];
  const float* cb    = (const float*)d_in[5];
  const float* csc   = (const float*)d_in[6];
  float* out = (float*)d_out;
  int nblk = (int)((BHW + 255) / 256);  // 2280

  if (ws_size >= (size_t)WS_NEED) {
    char* ws = (char*)d_ws;
    nhwc_kernel<<<dim3(Wc / 64, Hc, Bc), 256, 0, stream>>>(guid, ws);
    border_kernel<<<(Bc * (2 * WPAD + 2 * (HP - 2)) + 255) / 256, 256, 0, stream>>>(ws);
    wconv_kernel<<<72, 256, 0, stream>>>(cw, ws);

    dim3 pgrid(Wc / PC, Hc / PR, Bc);  // (19, 60, 2)
    conv_fused_kernel<<<pgrid, 256, 0, stream>>>(ws, cb, conf, csc, occ, initd, out);

    uint4* tab4 = (uint4*)ws;  // overlaps NHWC region (dead after conv_fused)
    prop_tab1_kernel<<<pgrid, 256, 0, stream>>>(out + OUT1, occ, initd, out, tab4);
    for (int t = 2; t < PROP; t++) {
      const float* dp = out + OUT1 + (long)(t - 1) * BHW;
      prop_tabN_kernel<<<pgrid, 256, 0, stream>>>(dp, tab4, out, t);
    }
  } else {
    conv_mfma_kernel<<<dim3(Wc / TX, Hc / TY, Bc), 256, 0, stream>>>(guid, cw, cb, out);
    prep_kernel<<<nblk, 256, 0, stream>>>(conf, csc, out);
    for (int t = 0; t < PROP; t++) {
      const float* dp = (t == 0) ? initd : (out + OUT1 + (long)(t - 1) * BHW);
      prop_kernel<<<nblk, 256, 0, stream>>>(dp, occ, initd, out, t);
    }
  }
}

// Round 18
// 194.508 us; speedup vs baseline: 1.2419x; 1.0351x over previous
//
#include <hip/hip_runtime.h>
#include <hip/hip_bf16.h>
#include <math.h>
#include <string.h>

typedef __attribute__((ext_vector_type(8))) short bf16x8;
typedef __attribute__((ext_vector_type(4))) float f32x4;

// Problem constants
constexpr int Bc = 2, CGc = 64, Hc = 240, Wc = 1216;
constexpr int IDXR = 4, PROP = 6;
constexpr long HW  = (long)Hc * Wc;      // 291840
constexpr long BHW = (long)Bc * HW;      // 583680

// d_out layout (floats)
constexpr long OUT0 = 0;
constexpr long OUT1 = BHW;
constexpr long OUT2 = BHW * 7;
constexpr long OUT3 = OUT2 + (long)Bc * 18 * HW;
constexpr long OUT4 = OUT3 + (long)Bc * 9 * HW;

// ---- padded NHWC bf16 guidance in ws: [b][py 0..241][px 0..1217][ic 0..63] --
constexpr int HP = Hc + 2, WPAD = Wc + 2;            // 242 x 1218
constexpr long APXB   = (long)HP * WPAD;
constexpr long A_TOT  = (long)Bc * APXB * 128;       // 75.5 MB
constexpr long WOFF   = A_TOT;
constexpr long WS_NEED = WOFF + (long)9 * 32 * 128;
// f16 prop-state table (overlaps NHWC region; written by prop step 1, read by
// steps 2..5): uint4 tab4[4][BHW] = 37.4 MB < A_TOT.

// prop tiling
constexpr int PR = 4, PC = 64, HLO = 6;
constexpr int TR = PR + 2 * HLO;        // 16 rows
constexpr int TC = PC + 2 * HLO + 1;    // 77 cols

__device__ __forceinline__ unsigned short f2bf(float f) {
  __hip_bfloat16 h = __float2bfloat16(f);
  return __builtin_bit_cast(unsigned short, h);
}
__device__ __forceinline__ unsigned short f2h(float f) {
  _Float16 h = (_Float16)f;
  return __builtin_bit_cast(unsigned short, h);
}
__device__ __forceinline__ float h2f(unsigned short u) {
  return (float)__builtin_bit_cast(_Float16, u);
}
// fast tanh: (e^{2x}-1)/(e^{2x}+1), clamped; err ~1e-7 vs tol 17
__device__ __forceinline__ float fast_tanh(float x) {
  float xc = fminf(fmaxf(x, -15.f), 15.f);
  float e = __expf(2.f * xc);
  return (e - 1.f) / (e + 1.f);
}

// horizontal pair load with zero padding; interior = one 8B load
__device__ __forceinline__ void row2(const float* __restrict__ img, int yy, int x0,
                                     float& a, float& b) {
  if (yy >= 0 && yy < Hc) {
    if (x0 >= 0 && x0 < Wc - 1) {
      float2 v;
      __builtin_memcpy(&v, img + (long)yy * Wc + x0, 8);
      a = v.x; b = v.y;
    } else {
      a = (x0 >= 0 && x0 < Wc)         ? img[(long)yy * Wc + x0]     : 0.f;
      b = (x0 + 1 >= 0 && x0 + 1 < Wc) ? img[(long)yy * Wc + x0 + 1] : 0.f;
    }
  } else { a = 0.f; b = 0.f; }
}

__device__ __forceinline__ float bilin(const float* __restrict__ img, float y, float x) {
  float y0f = floorf(y), x0f = floorf(x);
  int y0 = (int)y0f, x0 = (int)x0f;
  float wy = y - y0f, wx = x - x0f;
  float v00, v01, v10, v11;
  row2(img, y0,     x0, v00, v01);
  row2(img, y0 + 1, x0, v10, v11);
  float top = v00 + wx * (v01 - v00);
  float bot = v10 + wx * (v11 - v10);
  return top + wy * (bot - top);
}

// bilinear out of a staged tile with global fallback
__device__ __forceinline__ float bilin_tile(
    const float (*tile)[TC], const float* __restrict__ db,
    int y0, int x0, float sy, float sx) {
  float yf = floorf(sy), xf = floorf(sx);
  int iy = (int)yf, ix = (int)xf;
  float wy = sy - yf, wx = sx - xf;
  if (iy >= y0 - HLO && iy + 1 <= y0 + PR - 1 + HLO &&
      ix >= x0 - HLO && ix + 1 <= x0 + PC - 1 + HLO) {
    int ly = iy - (y0 - HLO), lx = ix - (x0 - HLO);
    float v00 = tile[ly][lx],     v01 = tile[ly][lx + 1];
    float v10 = tile[ly + 1][lx], v11 = tile[ly + 1][lx + 1];
    float top = v00 + wx * (v01 - v00);
    float bot = v10 + wx * (v11 - v10);
    return top + wy * (bot - top);
  }
  return bilin(db, sy, sx);
}

__device__ __forceinline__ void stage_tile(
    float (*tile)[TC], const float* __restrict__ db, int y0, int x0, int tid) {
  for (int i = tid; i < TR * TC; i += 256) {
    int rr = i / TC, cc = i - rr * TC;
    int gy = y0 - HLO + rr, gx = x0 - HLO + cc;
    tile[rr][cc] = (gy >= 0 && gy < Hc && gx >= 0 && gx < Wc)
                       ? db[(long)gy * Wc + gx] : 0.f;
  }
}

// ---------------- NCHW f32 -> padded NHWC bf16 (tiled transpose) -------------
__global__ __launch_bounds__(256) void nhwc_kernel(
    const float* __restrict__ g, char* __restrict__ ws) {
  __shared__ __align__(16) char tileb[64 * 132];
  const int tid = threadIdx.x;
  const int x0 = blockIdx.x * 64;
  const int y  = blockIdx.y;
  const int bz = blockIdx.z;
  const float* gb = g + (long)bz * CGc * HW + (long)y * Wc + x0;
  const int px = tid & 63, wv = tid >> 6;
#pragma unroll
  for (int k = 0; k < 16; ++k) {
    int ic = k * 4 + wv;
    float v = gb[(long)ic * HW + px];
    *reinterpret_cast<unsigned short*>(tileb + px * 132 + ic * 2) = f2bf(v);
  }
  __syncthreads();
  const int opx = tid >> 2, q = tid & 3;
  unsigned int u[8];
#pragma unroll
  for (int j = 0; j < 8; ++j)
    u[j] = *reinterpret_cast<unsigned int*>(tileb + opx * 132 + q * 32 + j * 4);
  char* dst = ws + ((long)(bz * HP + y + 1) * WPAD + x0 + 1 + opx) * 128 + q * 32;
  reinterpret_cast<uint4*>(dst)[0] = make_uint4(u[0], u[1], u[2], u[3]);
  reinterpret_cast<uint4*>(dst)[1] = make_uint4(u[4], u[5], u[6], u[7]);
}

// ---------------- zero the pad border ---------------------------------------
__global__ __launch_bounds__(256) void border_kernel(char* __restrict__ ws) {
  constexpr int NB = 2 * WPAD + 2 * (HP - 2);
  long i = (long)blockIdx.x * 256 + threadIdx.x;
  if (i >= (long)Bc * NB) return;
  int bz = (int)(i / NB);
  int r  = (int)(i - (long)bz * NB);
  int py, px;
  if (r < WPAD)            { py = 0;      px = r; }
  else if (r < 2 * WPAD)   { py = HP - 1; px = r - WPAD; }
  else { int qq = r - 2 * WPAD; py = 1 + (qq >> 1); px = (qq & 1) ? (WPAD - 1) : 0; }
  char* p = ws + ((long)(bz * HP + py) * WPAD + px) * 128;
  uint4 z = make_uint4(0, 0, 0, 0);
#pragma unroll
  for (int j = 0; j < 8; ++j) reinterpret_cast<uint4*>(p)[j] = z;
}

// ---------------- W: OIHW f32 -> [tap9][oc32][ic64] bf16 (72 blocks) ---------
__global__ __launch_bounds__(256) void wconv_kernel(
    const float* __restrict__ w, char* __restrict__ ws) {
  char* wd = ws + WOFF;
  int idx = blockIdx.x * 256 + threadIdx.x;
  if (idx < 24 * 64 * 9) {
    int oc = idx / 576, r = idx - oc * 576;
    int ic = r / 9, tap = r - ic * 9;
    *reinterpret_cast<unsigned short*>(wd + tap * 4096 + oc * 128 + ic * 2) = f2bf(w[idx]);
  } else if (idx < 32 * 64 * 9) {
    int i2 = idx - 24 * 64 * 9;
    int oc = 24 + i2 / 576, r = i2 % 576;
    int ic = r / 9, tap = r % 9;
    *reinterpret_cast<unsigned short*>(wd + tap * 4096 + oc * 128 + ic * 2) = 0;
  }
}

// ---------------- fused conv + prep + prop0 ----------------------------------
constexpr int CTILE_BYTES = 6 * 66 * 128;   // 50688
constexpr int CUNITS = CTILE_BYTES / 16;    // 3168
constexpr int EXST = 33;                    // bank step 1 -> 2-way (free)
constexpr int EXCH_BYTES = 4 * 64 * EXST * 4; // 33792
constexpr int DT_OFF = EXCH_BYTES;            // 33792
constexpr int CT_OFF = DT_OFF + TR * TC * 4;  // 38720; end 43648 <= 50688 ✓
constexpr int TILE_N = TR * TC;               // 1232

__global__ __launch_bounds__(256) void conv_fused_kernel(
    const char* __restrict__ ws, const float* __restrict__ bias,
    const float* __restrict__ conf, const float* __restrict__ scale_p,
    const float* __restrict__ occm, const float* __restrict__ initd,
    float* __restrict__ out) {
  __shared__ __align__(16) char smemA[CTILE_BYTES];
  const int tid  = threadIdx.x;
  const int lane = tid & 63, wv = tid >> 6;
  const int lrow = lane & 15, lgrp = lane >> 4;
  const int x0 = blockIdx.x * 64;
  const int y0 = blockIdx.y * 4;
  const int bz = blockIdx.z;

  // ---- phase 1: stage NHWC tile -> swizzled LDS; issue dtile/ctile loads ----
  const char* Abase = ws + ((long)(bz * HP + y0) * WPAD + x0) * 128;
#pragma unroll
  for (int it = 0; it < 13; ++it) {
    int u = it * 256 + tid;
    if (u < CUNITS) {
      int pxl = u >> 3, j = u & 7;
      int r = pxl / 66, col = pxl - r * 66;
      uint4 v = *reinterpret_cast<const uint4*>(
          Abase + ((long)r * WPAD + col) * 128 + j * 16);
      int ldsb = pxl * 128 + ((j ^ (col & 7)) << 4);
      *reinterpret_cast<uint4*>(smemA + ldsb) = v;
    }
  }

  // T14: issue disp/conf tile loads into regs; HBM latency hides under MFMA
  const float* db    = initd + (long)bz * HW;
  const float* confb = conf  + (long)bz * HW;
  float rD[5], rC[5];
#pragma unroll
  for (int k = 0; k < 5; ++k) {
    int i = k * 256 + tid;
    rD[k] = 0.f; rC[k] = 0.f;
    if (i < TILE_N) {
      int rr = i / TC, cc = i - rr * TC;
      int gy = y0 - HLO + rr, gx = x0 - HLO + cc;
      if (gy >= 0 && gy < Hc && gx >= 0 && gx < Wc) {
        long o = (long)gy * Wc + gx;
        rD[k] = db[o];
        rC[k] = confb[o];
      }
    }
  }
  __syncthreads();

  const char* Wb = ws + WOFF + (long)lrow * 128 + lgrp * 16;

  f32x4 acc[4][2];
#pragma unroll
  for (int h = 0; h < 4; ++h)
#pragma unroll
    for (int nt = 0; nt < 2; ++nt) acc[h][nt] = (f32x4){0.f, 0.f, 0.f, 0.f};

#pragma unroll
  for (int tap = 0; tap < 9; ++tap) {
    const int dy = tap / 3, dx = tap - dy * 3;
    const char* Wt = Wb + tap * 4096;
#pragma unroll
    for (int ks = 0; ks < 2; ++ks) {
      bf16x8 wf0 = *reinterpret_cast<const bf16x8*>(Wt + ks * 64);
      bf16x8 wf1 = *reinterpret_cast<const bf16x8*>(Wt + 2048 + ks * 64);
#pragma unroll
      for (int h = 0; h < 4; ++h) {
        const int colc = lrow + dx + h * 16;
        int abyte = ((wv + dy) * 66 + colc) * 128 +
                    ((((ks << 2) + lgrp) ^ (colc & 7)) << 4);
        bf16x8 af = *reinterpret_cast<const bf16x8*>(smemA + abyte);
        acc[h][0] = __builtin_amdgcn_mfma_f32_16x16x32_bf16(af, wf0, acc[h][0], 0, 0, 0);
        acc[h][1] = __builtin_amdgcn_mfma_f32_16x16x32_bf16(af, wf1, acc[h][1], 0, 0, 0);
      }
    }
  }
  __syncthreads();   // all reads done -> reuse smemA

  // ---- phase 2: exch writes + offset stores + tile ds_writes (merged) ----
  float* exch = reinterpret_cast<float*>(smemA);
  float* dflat = reinterpret_cast<float*>(smemA + DT_OFF);
  float* cflat = reinterpret_cast<float*>(smemA + CT_OFF);
  {
    const int y = y0 + wv;
#pragma unroll
    for (int h = 0; h < 4; ++h) {
      const int xx = x0 + h * 16 + lgrp * 4;
      const int lpx = h * 16 + lgrp * 4;
#pragma unroll
      for (int nt = 0; nt < 2; ++nt) {
        int oc = nt * 16 + lrow;
        if (oc >= 24) continue;
        float bv = bias[oc];
        f32x4 v = acc[h][nt];
#pragma unroll
        for (int j = 0; j < 4; ++j)
          exch[(wv * 64 + lpx + j) * EXST + oc] = v[j] + bv;
        if (oc < 16) {
          int n = oc >> 1, cd = oc & 1;
          int mm = (n < IDXR) ? n : n + 1;
          long dst = OUT2 + (long)(bz * 18 + 2 * mm + cd) * HW;
          float4 st = make_float4(v[0] + bv, v[1] + bv, v[2] + bv, v[3] + bv);
          *reinterpret_cast<float4*>(&out[dst + (long)y * Wc + xx]) = st;
        }
      }
    }
  }
#pragma unroll
  for (int k = 0; k < 5; ++k) {
    int i = k * 256 + tid;
    if (i < TILE_N) { dflat[i] = rD[k]; cflat[i] = rC[k]; }
  }
  __syncthreads();

  // ---- phase 3: px-major prep + prop0 ----
  float (*dtile)[TC] = reinterpret_cast<float (*)[TC]>(smemA + DT_OFF);
  float (*ctile)[TC] = reinterpret_cast<float (*)[TC]>(smemA + CT_OFF);
  const int row = tid >> 6, px = tid & 63;
  const int y = y0 + row, x = x0 + px;
  long rem = (long)y * Wc + x;
  long p = (long)bz * HW + rem;

  float ch[24];
#pragma unroll
  for (int j = 0; j < 24; ++j) ch[j] = exch[(row * 64 + px) * EXST + j];

  const float inv_scale = 1.f / (scale_p[0] + 1e-8f);
  float* off  = out + OUT2 + (long)bz * 18 * HW + rem;
  float* affp = out + OUT3 + (long)bz * 9  * HW + rem;

  float affr[9], oyr[9], oxr[9];
  float asum = 0.f;
#pragma unroll
  for (int m = 0; m < 8; m++) {
    int n = (m < IDXR) ? m : m + 1;
    float oy  = ch[2 * m];
    float ox  = ch[2 * m + 1];
    float raw = ch[16 + m];
    float avv = fast_tanh(raw) * inv_scale;
    float cs  = bilin_tile(ctile, confb, y0, x0, (float)y + oy, (float)x + ox);
    affr[n] = avv * cs;
    oyr[n] = oy; oxr[n] = ox;
    asum += fabsf(affr[n]);
  }
  float s = fmaxf(asum + 1e-5f, 1.0f);
  float inv_s = 1.f / s;
  float total = 0.f;
#pragma unroll
  for (int m = 0; m < 8; m++) {
    int n = (m < IDXR) ? m : m + 1;
    affr[n] *= inv_s; total += affr[n];
  }
  affr[IDXR] = 1.f - total;
  oyr[IDXR] = 0.f; oxr[IDXR] = 0.f;
#pragma unroll
  for (int n = 0; n < 9; n++) affp[(long)n * HW] = affr[n];
  off[(long)(2 * IDXR) * HW]     = 0.f;
  off[(long)(2 * IDXR + 1) * HW] = 0.f;
  if (p == 0) out[OUT4] = scale_p[0];

  // prop step 0
  float occv  = occm[p];
  float initv = dtile[HLO + row][HLO + px];
  float acc0 = 0.f;
#pragma unroll
  for (int k = 0; k < 9; k++) {
    float sy = (float)(y + k / 3 - 1) + oyr[k];
    float sx = (float)(x + k % 3 - 1) + oxr[k];
    acc0 = fmaf(affr[k], bilin_tile(dtile, db, y0, x0, sy, sx), acc0);
  }
  acc0 = fmaxf(acc0, 0.f);
  out[OUT1 + p] = (1.f - occv) * acc0 + occv * initv;
}

// ---------------- prop step 1: plane-read prop + f16 table write -------------
__global__ __launch_bounds__(256) void prop_tab1_kernel(
    const float* __restrict__ dispPrev,
    const float* __restrict__ occ, const float* __restrict__ initd,
    float* __restrict__ out, uint4* __restrict__ tab4) {
  __shared__ float tile[TR][TC];
  const int tid = threadIdx.x;
  const int x0 = blockIdx.x * PC;
  const int y0 = blockIdx.y * PR;
  const int b  = blockIdx.z;
  const float* db = dispPrev + (long)b * HW;
  stage_tile(tile, db, y0, x0, tid);
  __syncthreads();

  const int y = y0 + (tid >> 6);
  const int x = x0 + (tid & 63);
  long rem = (long)y * Wc + x;
  long p = (long)b * HW + rem;

  const float* off  = out + OUT2 + (long)b * 18 * HW + rem;
  const float* affp = out + OUT3 + (long)b * 9  * HW + rem;

  float affv[9], oyv[9], oxv[9];
#pragma unroll
  for (int k = 0; k < 9; k++) {
    oyv[k]  = off[(long)(2 * k) * HW];
    oxv[k]  = off[(long)(2 * k + 1) * HW];
    affv[k] = affp[(long)k * HW];
  }
  float occv  = occ[p];
  float initv = initd[p];

  float acc = 0.f;
#pragma unroll
  for (int k = 0; k < 9; k++) {
    float sy = (float)(y + k / 3 - 1) + oyv[k];
    float sx = (float)(x + k % 3 - 1) + oxv[k];
    acc = fmaf(affv[k], bilin_tile(tile, db, y0, x0, sy, sx), acc);
  }
  acc = fmaxf(acc, 0.f);
  float res = (1.f - occv) * acc + occv * initv;
  out[OUT1 + (long)1 * BHW + p] = res;

  // pack f16 state table
  unsigned short hs[28];
#pragma unroll
  for (int k = 0; k < 9; k++) {
    hs[k] = f2h(affv[k]); hs[9 + k] = f2h(oyv[k]); hs[18 + k] = f2h(oxv[k]);
  }
  hs[27] = 0;
  unsigned u[16];
#pragma unroll
  for (int i = 0; i < 14; i++)
    u[i] = (unsigned)hs[2 * i] | ((unsigned)hs[2 * i + 1] << 16);
  u[14] = __builtin_bit_cast(unsigned, occv);
  u[15] = __builtin_bit_cast(unsigned, initv);
#pragma unroll
  for (int g = 0; g < 4; g++)
    tab4[(long)g * BHW + p] = make_uint4(u[4 * g], u[4 * g + 1], u[4 * g + 2], u[4 * g + 3]);
}

// ---------------- prop steps 2..5: f16 table read -----------------------------
__global__ __launch_bounds__(256) void prop_tabN_kernel(
    const float* __restrict__ dispPrev, const uint4* __restrict__ tab4,
    float* __restrict__ out, int t) {
  __shared__ float tile[TR][TC];
  const int tid = threadIdx.x;
  const int x0 = blockIdx.x * PC;
  const int y0 = blockIdx.y * PR;
  const int b  = blockIdx.z;
  const float* db = dispPrev + (long)b * HW;
  stage_tile(tile, db, y0, x0, tid);
  __syncthreads();

  const int y = y0 + (tid >> 6);
  const int x = x0 + (tid & 63);
  long rem = (long)y * Wc + x;
  long p = (long)b * HW + rem;

  unsigned u[16];
#pragma unroll
  for (int g = 0; g < 4; g++) {
    uint4 q = tab4[(long)g * BHW + p];
    u[4 * g] = q.x; u[4 * g + 1] = q.y; u[4 * g + 2] = q.z; u[4 * g + 3] = q.w;
  }
  float fl[27];
#pragma unroll
  for (int i = 0; i < 27; i++) {
    unsigned w0 = u[i >> 1];
    fl[i] = h2f((unsigned short)((i & 1) ? (w0 >> 16) : (w0 & 0xffff)));
  }
  float occv  = __builtin_bit_cast(float, u[14]);
  float initv = __builtin_bit_cast(float, u[15]);

  float acc = 0.f;
#pragma unroll
  for (int k = 0; k < 9; k++) {
    float sy = (float)(y + k / 3 - 1) + fl[9 + k];
    float sx = (float)(x + k % 3 - 1) + fl[18 + k];
    acc = fmaf(fl[k], bilin_tile(tile, db, y0, x0, sy, sx), acc);
  }
  acc = fmaxf(acc, 0.f);
  float res = (1.f - occv) * acc + occv * initv;
  out[OUT1 + (long)t * BHW + p] = res;
  if (t == PROP - 1) out[OUT0 + p] = res;
}

// ================= legacy fallback path (ws too small) =======================
constexpr int TY = 8, TX = 32;
constexpr int AR = TY + 2, AC = TX + 2;
constexpr int A_BYTES = AR * AC * CGc * 2;
constexpr int W_BYTES = 9 * 32 * 32 * 2;

__global__ __launch_bounds__(256) void conv_mfma_kernel(
    const float* __restrict__ g, const float* __restrict__ wsrc,
    const float* __restrict__ bias, float* __restrict__ out) {
  __shared__ __align__(16) char smemA[A_BYTES];
  __shared__ __align__(16) char smemW[W_BYTES];
  const int tid = threadIdx.x;
  const int x0 = blockIdx.x * TX;
  const int y0 = blockIdx.y * TY;
  const int bz = blockIdx.z;
  const float* gb = g + (long)bz * CGc * HW;
  for (int w = tid; w < AR * AC * 32; w += 256) {
    int c  = w % AC;
    int t2 = w / AC;
    int icp = t2 & 31;
    int r   = t2 >> 5;
    int y = y0 + r - 1, x = x0 + c - 1;
    float v0 = 0.f, v1 = 0.f;
    if (y >= 0 && y < Hc && x >= 0 && x < Wc) {
      const float* p = gb + (long)(2 * icp) * HW + (long)y * Wc + x;
      v0 = p[0]; v1 = p[HW];
    }
    unsigned int pk = (unsigned int)f2bf(v0) | ((unsigned int)f2bf(v1) << 16);
    int byte = (r * AC + c) * 128 + icp * 4;
    byte ^= (c & 7) << 4;
    *reinterpret_cast<unsigned int*>(smemA + byte) = pk;
  }
  auto stageW = [&](int hs) {
    for (int idx = tid; idx < 24 * 32 * 9; idx += 256) {
      int oc  = idx / 288;
      int r1  = idx - oc * 288;
      int icl = r1 / 9;
      int tap = r1 - icl * 9;
      float f = wsrc[idx + 288 * (oc + hs)];
      int byte = (tap * 32 + oc) * 64 + icl * 2;
      byte ^= (oc & 7) << 4;
      *reinterpret_cast<unsigned short*>(smemW + byte) = f2bf(f);
    }
  };
  stageW(0);
  __syncthreads();
  const int wid  = tid >> 6;
  const int lane = tid & 63;
  const int lrow = lane & 15;
  const int lgrp = lane >> 4;
  f32x4 acc[4][2];
#pragma unroll
  for (int m = 0; m < 4; m++)
#pragma unroll
    for (int nt = 0; nt < 2; nt++) acc[m][nt] = (f32x4){0.f, 0.f, 0.f, 0.f};
  for (int ks = 0; ks < 2; ++ks) {
    if (ks) { __syncthreads(); stageW(1); __syncthreads(); }
#pragma unroll
    for (int tap = 0; tap < 9; ++tap) {
      const int dy = tap / 3, dx = tap - dy * 3;
      int bb = (tap * 32 + lrow) * 64 + lgrp * 16;
      int bbyte0 = bb ^ ((lrow & 7) << 4);
      int bbyte1 = (bb + 16 * 64) ^ ((lrow & 7) << 4);
      bf16x8 bf0 = *reinterpret_cast<const bf16x8*>(smemW + bbyte0);
      bf16x8 bf1 = *reinterpret_cast<const bf16x8*>(smemW + bbyte1);
#pragma unroll
      for (int dr = 0; dr < 2; ++dr) {
        const int rin = 2 * wid + dr + dy;
#pragma unroll
        for (int h = 0; h < 2; ++h) {
          const int cin = h * 16 + lrow + dx;
          int abyte = ((rin * AC + cin) * 128 + ks * 64 + lgrp * 16) ^ ((cin & 7) << 4);
          bf16x8 af = *reinterpret_cast<const bf16x8*>(smemA + abyte);
          acc[dr * 2 + h][0] = __builtin_amdgcn_mfma_f32_16x16x32_bf16(af, bf0, acc[dr * 2 + h][0], 0, 0, 0);
          acc[dr * 2 + h][1] = __builtin_amdgcn_mfma_f32_16x16x32_bf16(af, bf1, acc[dr * 2 + h][1], 0, 0, 0);
        }
      }
    }
  }
#pragma unroll
  for (int dr = 0; dr < 2; ++dr) {
    const int yy = y0 + 2 * wid + dr;
#pragma unroll
    for (int h = 0; h < 2; ++h) {
      const int xx = x0 + h * 16 + lgrp * 4;
#pragma unroll
      for (int nt = 0; nt < 2; ++nt) {
        int oc = nt * 16 + lrow;
        if (oc >= 24) continue;
        float bv = bias[oc];
        long dst;
        if (oc < 16) {
          int n = oc >> 1, cd = oc & 1;
          int mm = (n < IDXR) ? n : n + 1;
          dst = OUT2 + (long)(bz * 18 + 2 * mm + cd) * HW;
        } else {
          int i2 = oc - 16;
          int mm = (i2 < IDXR) ? i2 : i2 + 1;
          dst = OUT3 + (long)(bz * 9 + mm) * HW;
        }
        f32x4 v = acc[dr * 2 + h][nt];
        float4 st = make_float4(v[0] + bv, v[1] + bv, v[2] + bv, v[3] + bv);
        *reinterpret_cast<float4*>(&out[dst + (long)yy * Wc + xx]) = st;
      }
    }
  }
}

__global__ __launch_bounds__(256) void prep_kernel(
    const float* __restrict__ conf, const float* __restrict__ scale_p,
    float* __restrict__ out) {
  long p = (long)blockIdx.x * 256 + threadIdx.x;
  if (p >= BHW) return;
  int b = (int)(p / HW);
  long rem = p - (long)b * HW;
  int y = (int)(rem / Wc);
  int x = (int)(rem - (long)y * Wc);
  const float inv_scale = 1.f / (scale_p[0] + 1e-8f);
  const float* confb = conf + (long)b * HW;
  float* off  = out + OUT2 + (long)b * 18 * HW + rem;
  float* affp = out + OUT3 + (long)b * 9  * HW + rem;
  float a[8];
  float asum = 0.f;
#pragma unroll
  for (int m = 0; m < 8; m++) {
    int n = (m < IDXR) ? m : m + 1;
    float oy  = off[(long)(2 * n) * HW];
    float ox  = off[(long)(2 * n + 1) * HW];
    float raw = affp[(long)n * HW];
    float av  = tanhf(raw) * inv_scale;
    float cs  = bilin(confb, (float)y + oy, (float)x + ox);
    a[m] = av * cs;
    asum += fabsf(a[m]);
  }
  float s = fmaxf(asum + 1e-5f, 1.0f);
  float inv_s = 1.f / s;
  float total = 0.f;
#pragma unroll
  for (int m = 0; m < 8; m++) { a[m] *= inv_s; total += a[m]; }
  float aref = 1.f - total;
#pragma unroll
  for (int m = 0; m < 8; m++) {
    int n = (m < IDXR) ? m : m + 1;
    affp[(long)n * HW] = a[m];
  }
  affp[(long)IDXR * HW] = aref;
  off[(long)(2 * IDXR) * HW]     = 0.f;
  off[(long)(2 * IDXR + 1) * HW] = 0.f;
  if (p == 0) out[OUT4] = scale_p[0];
}

__global__ __launch_bounds__(256) void prop_kernel(
    const float* __restrict__ dispPrev,
    const float* __restrict__ occ, const float* __restrict__ initd,
    float* __restrict__ out, int t) {
  long p = (long)blockIdx.x * 256 + threadIdx.x;
  if (p >= BHW) return;
  int b = (int)(p / HW);
  long rem = p - (long)b * HW;
  int y = (int)(rem / Wc);
  int x = (int)(rem - (long)y * Wc);
  const float* off  = out + OUT2 + (long)b * 18 * HW + rem;
  const float* affp = out + OUT3 + (long)b * 9  * HW + rem;
  const float* db   = dispPrev + (long)b * HW;
  float acc = 0.f;
#pragma unroll
  for (int k = 0; k < 9; k++) {
    float oy = off[(long)(2 * k) * HW];
    float ox = off[(long)(2 * k + 1) * HW];
    float av = affp[(long)k * HW];
    float sy = (float)(y + k / 3 - 1) + oy;
    float sx = (float)(x + k % 3 - 1) + ox;
    acc = fmaf(av, bilin(db, sy, sx), acc);
  }
  acc = fmaxf(acc, 0.f);
  float o = occ[p];
  float res = (1.f - o) * acc + o * initd[p];
  out[OUT1 + (long)t * BHW + p] = res;
  if (t == PROP - 1) out[OUT0 + p] = res;
}

extern "C" void kernel_launch(void* const* d_in, const int* in_sizes, int n_in,
                              void* d_out, int out_size, void* d_ws, size_t ws_size,
                              hipStream_t stream) {
  const float* initd = (const float*)d_in[0];
  const float* occ   = (const float*)d_in[1];
  const float* conf  = (const float*)d_in[2];
  const float* guid  = (const float*)d_in[3];
  const float* cw    = (const float*)d_in[4];
  const float* cb    = (const float*)d_in[5];
  const float* csc   = (const float*)d_in[6];
  float* out = (float*)d_out;
  int nblk = (int)((BHW + 255) / 256);  // 2280

  if (ws_size >= (size_t)WS_NEED) {
    char* ws = (char*)d_ws;
    nhwc_kernel<<<dim3(Wc / 64, Hc, Bc), 256, 0, stream>>>(guid, ws);
    border_kernel<<<(Bc * (2 * WPAD + 2 * (HP - 2)) + 255) / 256, 256, 0, stream>>>(ws);
    wconv_kernel<<<72, 256, 0, stream>>>(cw, ws);

    dim3 pgrid(Wc / PC, Hc / PR, Bc);  // (19, 60, 2)
    conv_fused_kernel<<<pgrid, 256, 0, stream>>>(ws, cb, conf, csc, occ, initd, out);

    uint4* tab4 = (uint4*)ws;  // overlaps NHWC region (dead after conv_fused)
    prop_tab1_kernel<<<pgrid, 256, 0, stream>>>(out + OUT1, occ, initd, out, tab4);
    for (int t = 2; t < PROP; t++) {
      const float* dp = out + OUT1 + (long)(t - 1) * BHW;
      prop_tabN_kernel<<<pgrid, 256, 0, stream>>>(dp, tab4, out, t);
    }
  } else {
    conv_mfma_kernel<<<dim3(Wc / TX, Hc / TY, Bc), 256, 0, stream>>>(guid, cw, cb, out);
    prep_kernel<<<nblk, 256, 0, stream>>>(conf, csc, out);
    for (int t = 0; t < PROP; t++) {
      const float* dp = (t == 0) ? initd : (out + OUT1 + (long)(t - 1) * BHW);
      prop_kernel<<<nblk, 256, 0, stream>>>(dp, occ, initd, out, t);
    }
  }
}